// Round 1
// baseline (1980.889 us; speedup 1.0000x reference)
//
#include <hip/hip_runtime.h>
#include <math.h>

#define HID 128
#define KRBF 9
#define NLAYER 3

__device__ __forceinline__ float sp_(float x){ return fmaxf(x,0.f) + log1pf(expf(-fabsf(x))); }
__device__ __forceinline__ float sigm_(float x){ return 1.f/(1.f+expf(-x)); }
__device__ __forceinline__ float wsum64(float v){
  #pragma unroll
  for(int m=1;m<64;m<<=1) v += __shfl_xor(v,m,64);
  return v;
}
__device__ __forceinline__ int lb_(const int* __restrict__ a, int n, int key){
  int lo=0, hi=n;
  while(lo<hi){ int mid=(lo+hi)>>1; if(a[mid]<key) lo=mid+1; else hi=mid; }
  return lo;
}

// ---------------- edge features (E x 10) ----------------
__global__ void edge_prep(const float* __restrict__ pos, const float* __restrict__ ew,
                          const int* __restrict__ ei, float* __restrict__ efeat, int E){
  int e = blockIdx.x*256 + threadIdx.x;
  if(e>=E) return;
  int s = ei[e], d = ei[E+e];
  float dx = pos[d*3+0]-pos[s*3+0];
  float dy = pos[d*3+1]-pos[s*3+1];
  float dz = pos[d*3+2]-pos[s*3+2];
  float D = sqrtf(dx*dx+dy*dy+dz*dz);
  float x = D*0.1f;
  float cut = 0.f;
  if(x < 1.f){ float x3=x*x*x, x4=x3*x, x5=x4*x; cut = 1.f - 6.f*x5 + 15.f*x4 - 10.f*x3; }
  float ed = expf(-D);
  const double e10 = 4.5399929762484854e-05; // exp(-10)
  const float step  = (float)((e10 - 1.0)/8.0);
  const float width = (float)((4.5/(1.0-e10))*(4.5/(1.0-e10)));
  float* o = efeat + (size_t)e*10;
  #pragma unroll
  for(int k=0;k<KRBF;k++){
    float c = 1.0f + k*step;
    float dd = ed - c;
    o[k] = cut*expf(-width*dd*dd);
  }
  o[9] = ew[e];
}

// ---------------- CSR build ----------------
__global__ void csr_count(const int* __restrict__ ei, int* __restrict__ counts, int E){
  int e = blockIdx.x*256+threadIdx.x;
  if(e<E) atomicAdd(&counts[ei[E+e]],1);
}
__global__ void scan1(const int* __restrict__ counts, int* __restrict__ tmp,
                      int* __restrict__ bsums, int N){
  __shared__ int lds[256];
  int t = threadIdx.x; int idx = blockIdx.x*256+t;
  int v = (idx<N)? counts[idx]:0;
  lds[t]=v; __syncthreads();
  for(int off=1;off<256;off<<=1){
    int x = (t>=off)? lds[t-off]:0;
    __syncthreads();
    lds[t]+=x; __syncthreads();
  }
  if(idx<N) tmp[idx]=lds[t];
  if(t==255) bsums[blockIdx.x]=lds[255];
}
__global__ void scan2(const int* __restrict__ bsums, int* __restrict__ boffs, int nb){
  __shared__ int lds[256];
  int t=threadIdx.x;
  int v = (t<nb)? bsums[t]:0;
  lds[t]=v; __syncthreads();
  for(int off=1;off<256;off<<=1){
    int x=(t>=off)?lds[t-off]:0;
    __syncthreads();
    lds[t]+=x; __syncthreads();
  }
  if(t<nb) boffs[t] = lds[t]-v; // exclusive
}
__global__ void finalize_rs(const int* __restrict__ tmp, const int* __restrict__ boffs,
                            int* __restrict__ row_start, int N){
  int idx = blockIdx.x*256+threadIdx.x;
  if(idx<N) row_start[idx+1] = tmp[idx] + boffs[idx>>8];
  if(idx==0) row_start[0]=0;
}
__global__ void csr_scatter(const int* __restrict__ ei, const int* __restrict__ row_start,
                            int* __restrict__ counts2, int* __restrict__ csr, int E){
  int e = blockIdx.x*256+threadIdx.x;
  if(e>=E) return;
  int d = ei[E+e];
  int pos = row_start[d] + atomicAdd(&counts2[d],1);
  csr[pos]=e;
}

// ---------------- LayerNorm (wave per node) ----------------
__global__ void ln_node(const float* __restrict__ h, const float* __restrict__ g,
                        const float* __restrict__ b, float* __restrict__ hn, int N){
  int n = blockIdx.x*4 + (threadIdx.x>>6);
  if(n>=N) return;
  int lane = threadIdx.x & 63;
  int c = 2*lane;
  float2 v = *(const float2*)&h[(size_t)n*HID + c];
  float s1 = wsum64(v.x+v.y);
  float s2 = wsum64(v.x*v.x+v.y*v.y);
  float mu = s1*(1.f/HID);
  float var = s2*(1.f/HID) - mu*mu;
  float rs = rsqrtf(var + 1e-5f);
  float2 o;
  o.x = (v.x-mu)*rs*g[c]   + b[c];
  o.y = (v.y-mu)*rs*g[c+1] + b[c+1];
  *(float2*)&hn[(size_t)n*HID + c] = o;
}

// ---------------- fp32 GEMM: out[N x 128] (+bias, act, residual), tiled 64x64 ----------------
__global__ __launch_bounds__(256) void gemm128(
    const float* __restrict__ A, const float* __restrict__ W,
    const float* __restrict__ bias, const float* __restrict__ res,
    float* __restrict__ out, int N, int ostride, int ocol0, int act){
  __shared__ __align__(16) float As[64][132];
  __shared__ __align__(16) float Ws[64][64];
  int row0 = blockIdx.x*64, col0 = blockIdx.y*64;
  int tid = threadIdx.x;
  #pragma unroll
  for(int i=0;i<8;i++){
    int flat = (tid + 256*i)*4;
    int r = flat>>7, c = flat&127;
    float4 v = make_float4(0.f,0.f,0.f,0.f);
    if(row0+r < N) v = *(const float4*)&A[(size_t)(row0+r)*HID + c];
    *(float4*)&As[r][c] = v;
  }
  float acc[4][4] = {};
  int ty = tid>>4, tx = tid&15;
  for(int kk=0; kk<128; kk+=64){
    __syncthreads();
    #pragma unroll
    for(int i=0;i<4;i++){
      int flat = (tid + 256*i)*4;
      int r = flat>>6, c = flat&63;
      *(float4*)&Ws[r][c] = *(const float4*)&W[(size_t)(kk+r)*HID + col0 + c];
    }
    __syncthreads();
    #pragma unroll
    for(int k=0;k<64;k+=4){
      float4 av[4];
      #pragma unroll
      for(int i=0;i<4;i++) av[i] = *(const float4*)&As[ty*4+i][kk+k];
      #pragma unroll
      for(int kq=0;kq<4;kq++){
        float4 wq = *(const float4*)&Ws[k+kq][tx*4];
        float wv[4] = {wq.x, wq.y, wq.z, wq.w};
        float aa[4];
        #pragma unroll
        for(int i=0;i<4;i++){
          float4 aq = av[i];
          aa[i] = (kq==0)?aq.x:((kq==1)?aq.y:((kq==2)?aq.z:aq.w));
        }
        #pragma unroll
        for(int i=0;i<4;i++)
          #pragma unroll
          for(int j=0;j<4;j++)
            acc[i][j] = fmaf(aa[i], wv[j], acc[i][j]);
      }
    }
  }
  #pragma unroll
  for(int i=0;i<4;i++){
    int row = row0 + ty*4 + i;
    if(row >= N) continue;
    int colJ = col0 + tx*4;
    float4 v; float* vp = (float*)&v;
    #pragma unroll
    for(int j=0;j<4;j++){
      float t = acc[i][j] + bias[colJ+j];
      if(act==1) t = sp_(t);
      if(res) t += res[(size_t)row*ostride + ocol0 + colJ + j];
      vp[j] = t;
    }
    *(float4*)&out[(size_t)row*ostride + ocol0 + colJ] = v;
  }
}

// ---------------- attention logits (half-wave per edge) ----------------
__global__ void attn_logits(const float* __restrict__ qkvs, const float* __restrict__ efeat,
                            const float* __restrict__ WeL, const int* __restrict__ ei,
                            float* __restrict__ logits, int E){
  int t = blockIdx.x*256 + threadIdx.x;
  int e = t>>5;
  if(e>=E) return;
  int l32 = t & 31;
  int s = ei[e], d = ei[E+e];
  const float* qp = qkvs + (size_t)d*512;
  const float* kp = qkvs + (size_t)s*512 + 128;
  float4 q = *(const float4*)&qp[4*l32];
  float4 k = *(const float4*)&kp[4*l32];
  const float* ef = efeat + (size_t)e*10;
  float ea0=0.f, ea1=0.f, ea2=0.f, ea3=0.f;
  #pragma unroll
  for(int r=0;r<10;r++){
    float f = ef[r];
    float4 w = *(const float4*)&WeL[r*HID + 4*l32];
    ea0 = fmaf(f,w.x,ea0); ea1=fmaf(f,w.y,ea1); ea2=fmaf(f,w.z,ea2); ea3=fmaf(f,w.w,ea3);
  }
  float p = q.x*(k.x+ea0) + q.y*(k.y+ea1) + q.z*(k.z+ea2) + q.w*(k.w+ea3);
  p += __shfl_xor(p,1,64); p += __shfl_xor(p,2,64); p += __shfl_xor(p,4,64);
  if((l32&7)==0) logits[(size_t)e*4 + (l32>>3)] = p * 0.17677669529663687f;
}

// ---------------- softmax + message aggregation (wave per node, CSR) ----------------
__global__ void attn_agg(const float* __restrict__ qkvs, const float* __restrict__ efeat,
                         const float* __restrict__ WeL, const int* __restrict__ ei,
                         const int* __restrict__ row_start, const int* __restrict__ csr,
                         const float* __restrict__ logits, float* __restrict__ att, int N){
  int n = blockIdx.x*4 + (threadIdx.x>>6);
  if(n>=N) return;
  int lane = threadIdx.x&63;
  int head = lane>>4;
  int c0 = 2*lane;
  int lo = row_start[n], hi = row_start[n+1];
  float m = -1e30f;
  for(int i=lo;i<hi;i++){
    int e = csr[i];
    m = fmaxf(m, logits[(size_t)e*4+head]);
  }
  float ssum = 0.f, a0=0.f, a1=0.f;
  for(int i=lo;i<hi;i++){
    int e = csr[i];
    float w = expf(logits[(size_t)e*4+head] - m);
    ssum += w;
    int s = ei[e];
    const float* ef = efeat + (size_t)e*10;
    float ea0=0.f, ea1=0.f;
    #pragma unroll
    for(int r=0;r<10;r++){
      float f = ef[r];
      ea0 = fmaf(f, WeL[r*HID+c0],   ea0);
      ea1 = fmaf(f, WeL[r*HID+c0+1], ea1);
    }
    float2 v = *(const float2*)&qkvs[(size_t)s*512 + 256 + c0];
    a0 = fmaf(w, v.x+ea0, a0);
    a1 = fmaf(w, v.y+ea1, a1);
  }
  float inv = (hi>lo)? 1.f/ssum : 0.f;
  att[(size_t)n*HID+c0]   = a0*inv;
  att[(size_t)n*HID+c0+1] = a1*inv;
}

// ---------------- beta-gate + residual + softplus + LN (wave per node) ----------------
__global__ void combine_ln(const float* __restrict__ att, const float* __restrict__ qkvs,
                           const float* __restrict__ hn, const float* __restrict__ Wb,
                           const float* __restrict__ g, const float* __restrict__ b,
                           float* __restrict__ hn2, int N){
  int n = blockIdx.x*4 + (threadIdx.x>>6);
  if(n>=N) return;
  int lane = threadIdx.x&63;
  int c = 2*lane;
  float2 o  = *(const float2*)&att[(size_t)n*HID+c];
  float2 xr = *(const float2*)&qkvs[(size_t)n*512 + 384 + c];
  float bl = o.x*Wb[c] + o.y*Wb[c+1]
           + xr.x*Wb[HID+c] + xr.y*Wb[HID+c+1]
           + (o.x-xr.x)*Wb[2*HID+c] + (o.y-xr.y)*Wb[2*HID+c+1];
  bl = wsum64(bl);
  float beta = sigm_(bl);
  float u0 = beta*xr.x + (1.f-beta)*o.x;
  float u1 = beta*xr.y + (1.f-beta)*o.y;
  float2 hnv = *(const float2*)&hn[(size_t)n*HID+c];
  float h0 = hnv.x + sp_(u0);
  float h1 = hnv.y + sp_(u1);
  float s1 = wsum64(h0+h1);
  float s2 = wsum64(h0*h0+h1*h1);
  float mu = s1*(1.f/HID);
  float var = s2*(1.f/HID)-mu*mu;
  float rs = rsqrtf(var+1e-5f);
  float2 out;
  out.x = (h0-mu)*rs*g[c]+b[c];
  out.y = (h1-mu)*rs*g[c+1]+b[c+1];
  *(float2*)&hn2[(size_t)n*HID+c] = out;
}

// ---------------- pooling + output head (block per graph) ----------------
__global__ void pool_head(const float* __restrict__ h, const int* __restrict__ batch,
                          const float* __restrict__ Wo1, const float* __restrict__ bo1,
                          const float* __restrict__ Wo2, const float* __restrict__ bo2,
                          float* __restrict__ out, int N){
  int gid = blockIdx.x;
  int t = threadIdx.x;  // 128 threads
  int lo = lb_(batch, N, gid), hi = lb_(batch, N, gid+1);
  __shared__ float pl[128];
  __shared__ float red[128];
  float s = 0.f;
  for(int i=lo;i<hi;i++) s += h[(size_t)i*HID + t];
  pl[t] = s;
  __syncthreads();
  float acc = bo1[t];
  for(int c=0;c<128;c++) acc = fmaf(pl[c], Wo1[c*HID+t], acc);
  red[t] = sp_(acc)*Wo2[t];
  __syncthreads();
  for(int off=64;off>0;off>>=1){
    if(t<off) red[t]+=red[t+off];
    __syncthreads();
  }
  if(t==0) out[gid] = red[0] + bo2[0];
}

extern "C" void kernel_launch(void* const* d_in, const int* in_sizes, int n_in,
                              void* d_out, int out_size, void* d_ws, size_t ws_size,
                              hipStream_t stream){
  const float* h_in = (const float*)d_in[0];
  const float* pos  = (const float*)d_in[1];
  const float* ew   = (const float*)d_in[2];
  const float* Wq = (const float*)d_in[3];  const float* bq = (const float*)d_in[4];
  const float* Wk = (const float*)d_in[5];  const float* bk = (const float*)d_in[6];
  const float* Wv = (const float*)d_in[7];  const float* bv = (const float*)d_in[8];
  const float* We = (const float*)d_in[9];
  const float* Wsk= (const float*)d_in[10]; const float* bsk=(const float*)d_in[11];
  const float* Wbeta=(const float*)d_in[12];
  const float* W1=(const float*)d_in[13]; const float* b1=(const float*)d_in[14];
  const float* W2=(const float*)d_in[15]; const float* b2=(const float*)d_in[16];
  const float* W3=(const float*)d_in[17]; const float* b3=(const float*)d_in[18];
  const float* lng=(const float*)d_in[19]; const float* lnb=(const float*)d_in[20];
  const float* Wo1=(const float*)d_in[21]; const float* bo1=(const float*)d_in[22];
  const float* Wo2=(const float*)d_in[23]; const float* bo2=(const float*)d_in[24];
  const int* ei    = (const int*)d_in[25];
  const int* batch = (const int*)d_in[26];
  int N = in_sizes[0]/HID;
  int E = in_sizes[2];
  int G = out_size;
  float* out = (float*)d_out;

  char* ws = (char*)d_ws;
  size_t off=0;
  auto alloc=[&](size_t bytes)->char*{
    char* p = ws + off;
    off = (off + bytes + 255) & ~(size_t)255;
    return p;
  };
  float* efeat =(float*)alloc((size_t)E*10*4);
  int* counts  =(int*)  alloc((size_t)N*4);
  int* counts2 =(int*)  alloc((size_t)N*4);
  int* rowst   =(int*)  alloc((size_t)(N+1)*4);
  int* tmp     =(int*)  alloc((size_t)N*4);
  int* bsums   =(int*)  alloc(256*4);
  int* boffs   =(int*)  alloc(256*4);
  int* csr     =(int*)  alloc((size_t)E*4);
  float* hn    =(float*)alloc((size_t)N*HID*4);
  float* hn2   =(float*)alloc((size_t)N*HID*4);
  float* qkvs  =(float*)alloc((size_t)N*512*4);
  float* logits=(float*)alloc((size_t)E*4*4);
  float* att   =(float*)alloc((size_t)N*HID*4);
  float* hcur  =(float*)alloc((size_t)N*HID*4);

  int ebl = (E+255)/256;
  int nb  = (N+255)/256;
  int nwb = (N+3)/4;
  dim3 ggrid((N+63)/64, 2);

  edge_prep<<<ebl,256,0,stream>>>(pos,ew,ei,efeat,E);
  hipMemsetAsync(counts, 0, (size_t)N*4, stream);
  hipMemsetAsync(counts2,0, (size_t)N*4, stream);
  csr_count<<<ebl,256,0,stream>>>(ei,counts,E);
  scan1<<<nb,256,0,stream>>>(counts,tmp,bsums,N);
  scan2<<<1,256,0,stream>>>(bsums,boffs,nb);
  finalize_rs<<<nb,256,0,stream>>>(tmp,boffs,rowst,N);
  csr_scatter<<<ebl,256,0,stream>>>(ei,rowst,counts2,csr,E);

  const float* hprev = h_in;
  for(int l=0;l<NLAYER;l++){
    const float* Wq_l = Wq + (size_t)l*HID*HID; const float* bq_l = bq + (size_t)l*HID;
    const float* Wk_l = Wk + (size_t)l*HID*HID; const float* bk_l = bk + (size_t)l*HID;
    const float* Wv_l = Wv + (size_t)l*HID*HID; const float* bv_l = bv + (size_t)l*HID;
    const float* Ws_l = Wsk+ (size_t)l*HID*HID; const float* bs_l = bsk+ (size_t)l*HID;
    const float* We_l = We + (size_t)l*(KRBF+1)*HID;
    const float* Wb_l = Wbeta + (size_t)l*3*HID;
    const float* W1_l = W1 + (size_t)l*HID*HID; const float* b1_l = b1 + (size_t)l*HID;
    const float* W2_l = W2 + (size_t)l*HID*HID; const float* b2_l = b2 + (size_t)l*HID;
    const float* W3_l = W3 + (size_t)l*HID*HID; const float* b3_l = b3 + (size_t)l*HID;

    ln_node<<<nwb,256,0,stream>>>(hprev,lng,lnb,hn,N);
    gemm128<<<ggrid,256,0,stream>>>(hn,Wq_l,bq_l,nullptr,qkvs,N,512,  0,0);
    gemm128<<<ggrid,256,0,stream>>>(hn,Wk_l,bk_l,nullptr,qkvs,N,512,128,0);
    gemm128<<<ggrid,256,0,stream>>>(hn,Wv_l,bv_l,nullptr,qkvs,N,512,256,0);
    gemm128<<<ggrid,256,0,stream>>>(hn,Ws_l,bs_l,nullptr,qkvs,N,512,384,0);
    attn_logits<<<(E+7)/8,256,0,stream>>>(qkvs,efeat,We_l,ei,logits,E);
    attn_agg<<<nwb,256,0,stream>>>(qkvs,efeat,We_l,ei,rowst,csr,logits,att,N);
    combine_ln<<<nwb,256,0,stream>>>(att,qkvs,hn,Wb_l,lng,lnb,hn2,N);
    float* f1 = qkvs;
    float* f2 = qkvs + (size_t)N*HID;
    gemm128<<<ggrid,256,0,stream>>>(hn2,W1_l,b1_l,nullptr,f1,N,HID,0,1);
    gemm128<<<ggrid,256,0,stream>>>(f1, W2_l,b2_l,nullptr,f2,N,HID,0,1);
    gemm128<<<ggrid,256,0,stream>>>(f2, W3_l,b3_l,hn2,    hcur,N,HID,0,1);
    hprev = hcur;
  }
  pool_head<<<G,128,0,stream>>>(hcur,batch,Wo1,bo1,Wo2,bo2,out,N);
}

// Round 2
// 1225.911 us; speedup vs baseline: 1.6159x; 1.6159x over previous
//
#include <hip/hip_runtime.h>
#include <hip/hip_bf16.h>
#include <math.h>

#define HID 128
#define KRBF 9
#define NLAYER 3

typedef __attribute__((ext_vector_type(8))) short bf16x8;
typedef __attribute__((ext_vector_type(4))) float f32x4;

__device__ __forceinline__ float sp_(float x){ return fmaxf(x,0.f) + log1pf(expf(-fabsf(x))); }
__device__ __forceinline__ float sigm_(float x){ return 1.f/(1.f+expf(-x)); }
__device__ __forceinline__ float wsum64(float v){
  #pragma unroll
  for(int m=1;m<64;m<<=1) v += __shfl_xor(v,m,64);
  return v;
}
__device__ __forceinline__ float wsum16(float v){
  #pragma unroll
  for(int m=1;m<16;m<<=1) v += __shfl_xor(v,m,64);
  return v;
}
__device__ __forceinline__ float2 ldbf2(const __hip_bfloat16* p){
  __hip_bfloat162 b = *(const __hip_bfloat162*)p;
  return make_float2(__bfloat162float(b.x), __bfloat162float(b.y));
}
__device__ __forceinline__ int lb_(const int* __restrict__ a, int n, int key){
  int lo=0, hi=n;
  while(lo<hi){ int mid=(lo+hi)>>1; if(a[mid]<key) lo=mid+1; else hi=mid; }
  return lo;
}

// ---------------- edge features (E x 10) ----------------
__global__ void edge_prep(const float* __restrict__ pos, const float* __restrict__ ew,
                          const int* __restrict__ ei, float* __restrict__ efeat, int E){
  int e = blockIdx.x*256 + threadIdx.x;
  if(e>=E) return;
  int s = ei[e], d = ei[E+e];
  float dx = pos[d*3+0]-pos[s*3+0];
  float dy = pos[d*3+1]-pos[s*3+1];
  float dz = pos[d*3+2]-pos[s*3+2];
  float D = sqrtf(dx*dx+dy*dy+dz*dz);
  float x = D*0.1f;
  float cut = 0.f;
  if(x < 1.f){ float x3=x*x*x, x4=x3*x, x5=x4*x; cut = 1.f - 6.f*x5 + 15.f*x4 - 10.f*x3; }
  float ed = expf(-D);
  const double e10 = 4.5399929762484854e-05; // exp(-10)
  const float step  = (float)((e10 - 1.0)/8.0);
  const float width = (float)((4.5/(1.0-e10))*(4.5/(1.0-e10)));
  float* o = efeat + (size_t)e*10;
  #pragma unroll
  for(int k=0;k<KRBF;k++){
    float c = 1.0f + k*step;
    float dd = ed - c;
    o[k] = cut*expf(-width*dd*dd);
  }
  o[9] = ew[e];
}

// ---------------- CSR build ----------------
__global__ void csr_count(const int* __restrict__ ei, int* __restrict__ counts, int E){
  int e = blockIdx.x*256+threadIdx.x;
  if(e<E) atomicAdd(&counts[ei[E+e]],1);
}
__global__ void scan1(const int* __restrict__ counts, int* __restrict__ tmp,
                      int* __restrict__ bsums, int N){
  __shared__ int lds[256];
  int t = threadIdx.x; int idx = blockIdx.x*256+t;
  int v = (idx<N)? counts[idx]:0;
  lds[t]=v; __syncthreads();
  for(int off=1;off<256;off<<=1){
    int x = (t>=off)? lds[t-off]:0;
    __syncthreads();
    lds[t]+=x; __syncthreads();
  }
  if(idx<N) tmp[idx]=lds[t];
  if(t==255) bsums[blockIdx.x]=lds[255];
}
__global__ void scan2(const int* __restrict__ bsums, int* __restrict__ boffs, int nb){
  __shared__ int lds[256];
  int t=threadIdx.x;
  int v = (t<nb)? bsums[t]:0;
  lds[t]=v; __syncthreads();
  for(int off=1;off<256;off<<=1){
    int x=(t>=off)?lds[t-off]:0;
    __syncthreads();
    lds[t]+=x; __syncthreads();
  }
  if(t<nb) boffs[t] = lds[t]-v; // exclusive
}
__global__ void finalize_rs(const int* __restrict__ tmp, const int* __restrict__ boffs,
                            int* __restrict__ row_start, int N){
  int idx = blockIdx.x*256+threadIdx.x;
  if(idx<N) row_start[idx+1] = tmp[idx] + boffs[idx>>8];
  if(idx==0) row_start[0]=0;
}
__global__ void csr_scatter(const int* __restrict__ ei, const int* __restrict__ row_start,
                            int* __restrict__ counts2, int* __restrict__ csr, int E){
  int e = blockIdx.x*256+threadIdx.x;
  if(e>=E) return;
  int d = ei[E+e];
  int pos = row_start[d] + atomicAdd(&counts2[d],1);
  csr[pos]=e;
}

// ---------------- weight packing (fp32 -> bf16, B^T layout [outcol][k]) ----------------
__global__ void pack_w(const float* __restrict__ Wq, const float* __restrict__ Wk,
                       const float* __restrict__ Wv, const float* __restrict__ Wsk,
                       const float* __restrict__ bq, const float* __restrict__ bk,
                       const float* __restrict__ bv, const float* __restrict__ bsk,
                       const float* __restrict__ W1, const float* __restrict__ W2,
                       const float* __restrict__ W3,
                       __hip_bfloat16* __restrict__ Wqkvs, float* __restrict__ bqkvs,
                       __hip_bfloat16* __restrict__ Wffn){
  int idx = blockIdx.x*256 + threadIdx.x;
  const int QT = NLAYER*512*128;         // 196608
  const int FT = NLAYER*3*128*128;       // 147456
  if(idx < QT){
    int k = idx & 127; int n = (idx>>7)&511; int l = idx>>16;
    const float* src = (n<128)?Wq:((n<256)?Wk:((n<384)?Wv:Wsk));
    int col = n&127;
    Wqkvs[idx] = __float2bfloat16(src[(size_t)l*16384 + k*128 + col]);
  } else if(idx < QT+FT){
    int j = idx - QT;
    int k = j & 127; int n = (j>>7)&127; int f = (j>>14)%3; int l = j/(3*16384);
    const float* src = (f==0)?W1:((f==1)?W2:W3);
    Wffn[j] = __float2bfloat16(src[(size_t)l*16384 + k*128 + n]);
  } else if(idx < QT+FT+NLAYER*512){
    int j = idx - QT - FT;
    int n = j & 511; int l = j>>9;
    const float* src = (n<128)?bq:((n<256)?bk:((n<384)?bv:bsk));
    bqkvs[j] = src[l*128 + (n&127)];
  }
}

// ---------------- LayerNorm (wave per node) fp32 -> bf16 ----------------
__global__ void ln_node(const float* __restrict__ h, const float* __restrict__ g,
                        const float* __restrict__ b, __hip_bfloat16* __restrict__ hn, int N){
  int n = blockIdx.x*4 + (threadIdx.x>>6);
  if(n>=N) return;
  int lane = threadIdx.x & 63;
  int c = 2*lane;
  float2 v = *(const float2*)&h[(size_t)n*HID + c];
  float s1 = wsum64(v.x+v.y);
  float s2 = wsum64(v.x*v.x+v.y*v.y);
  float mu = s1*(1.f/HID);
  float var = s2*(1.f/HID) - mu*mu;
  float rs = rsqrtf(var + 1e-5f);
  __hip_bfloat162 o;
  o.x = __float2bfloat16((v.x-mu)*rs*g[c]   + b[c]);
  o.y = __float2bfloat16((v.y-mu)*rs*g[c+1] + b[c+1]);
  *(__hip_bfloat162*)&hn[(size_t)n*HID + c] = o;
}

// ---------------- MFMA bf16 GEMM: out[N x ncols] = A[N x 128] @ Wt^T ----------------
// Wt is [ncols][128] (k contiguous). Tile 128 rows x 64 cols, 4 waves.
__global__ __launch_bounds__(256) void gemm_mfma(
    const __hip_bfloat16* __restrict__ A, const __hip_bfloat16* __restrict__ Wt,
    const float* __restrict__ bias, const __hip_bfloat16* __restrict__ res,
    void* __restrict__ outp, int N, int ostride, int act, int out_f32){
  __shared__ __hip_bfloat16 As[128][136];
  __shared__ __hip_bfloat16 Ws[64][136];
  int row0 = blockIdx.y*128;
  int col0 = blockIdx.x*64;
  int tid = threadIdx.x;
  {
    int chunk = tid&15; int rbase = tid>>4;
    #pragma unroll
    for(int i=0;i<8;i++){
      int r = rbase + 16*i;
      int row = row0 + r;
      float4 v = make_float4(0.f,0.f,0.f,0.f);
      if(row < N) v = *(const float4*)&A[(size_t)row*128 + chunk*8];
      *(float4*)&As[r][chunk*8] = v;
    }
    #pragma unroll
    for(int i=0;i<4;i++){
      int c = rbase + 16*i;
      *(float4*)&Ws[c][chunk*8] = *(const float4*)&Wt[(size_t)(col0+c)*128 + chunk*8];
    }
  }
  __syncthreads();
  int wave = tid>>6, lane = tid&63;
  int m0 = wave*32;
  int ql = lane>>4;
  int il = lane&15;
  f32x4 acc[2][4];
  #pragma unroll
  for(int mi=0;mi<2;mi++)
    #pragma unroll
    for(int nj=0;nj<4;nj++)
      acc[mi][nj] = (f32x4){0.f,0.f,0.f,0.f};
  #pragma unroll
  for(int kk=0;kk<128;kk+=32){
    bf16x8 a0 = *(bf16x8*)&As[m0+il][kk+ql*8];
    bf16x8 a1 = *(bf16x8*)&As[m0+16+il][kk+ql*8];
    bf16x8 bb[4];
    #pragma unroll
    for(int nj=0;nj<4;nj++) bb[nj] = *(bf16x8*)&Ws[nj*16+il][kk+ql*8];
    #pragma unroll
    for(int nj=0;nj<4;nj++){
      acc[0][nj] = __builtin_amdgcn_mfma_f32_16x16x32_bf16(a0, bb[nj], acc[0][nj], 0,0,0);
      acc[1][nj] = __builtin_amdgcn_mfma_f32_16x16x32_bf16(a1, bb[nj], acc[1][nj], 0,0,0);
    }
  }
  #pragma unroll
  for(int mi=0;mi<2;mi++){
    int rowb = row0 + m0 + mi*16 + ql*4;
    #pragma unroll
    for(int r=0;r<4;r++){
      int rr = rowb + r;
      if(rr >= N) continue;
      #pragma unroll
      for(int nj=0;nj<4;nj++){
        int cg = col0 + nj*16 + il;
        float t = acc[mi][nj][r] + bias[cg];
        if(act) t = sp_(t);
        if(res) t += __bfloat162float(res[(size_t)rr*128 + cg]);
        if(out_f32) ((float*)outp)[(size_t)rr*ostride + cg] = t;
        else ((__hip_bfloat16*)outp)[(size_t)rr*ostride + cg] = __float2bfloat16(t);
      }
    }
  }
}

// ---------------- fused attention: logits + online softmax + aggregation ----------------
// wave per node. qkvs bf16 rows of 512 (q|k|v|skip). Uses linearity of ea=efeat@We:
// logit = q.k + sum_r efeat_r*(q.We_r); msg-sum = sum(w*v) + (sum_r S_r We_r), S_r=sum(w*efeat_r)
__global__ void attn_fused(const __hip_bfloat16* __restrict__ qkvs,
                           const float* __restrict__ efeat, const float* __restrict__ WeL,
                           const int* __restrict__ ei, const int* __restrict__ rowst,
                           const int* __restrict__ csr, float* __restrict__ att, int N){
  int n = blockIdx.x*4 + (threadIdx.x>>6);
  if(n>=N) return;
  int lane = threadIdx.x&63;
  int c0 = 2*lane;
  float2 q = ldbf2(&qkvs[(size_t)n*512 + c0]);
  float QW[10];
  #pragma unroll
  for(int r=0;r<10;r++){
    float t = q.x*WeL[r*HID+c0] + q.y*WeL[r*HID+c0+1];
    QW[r] = wsum16(t);
  }
  int lo = rowst[n], hi = rowst[n+1];
  float m = -1e30f, ssum = 0.f, a0 = 0.f, a1 = 0.f;
  float S[10];
  #pragma unroll
  for(int r=0;r<10;r++) S[r]=0.f;
  for(int i=lo;i<hi;i++){
    int e = csr[i];
    int s = ei[e];
    float2 kv = ldbf2(&qkvs[(size_t)s*512 + 128 + c0]);
    float d = q.x*kv.x + q.y*kv.y;
    d = wsum16(d);
    const float* ef = efeat + (size_t)e*10;
    float efr[10];
    #pragma unroll
    for(int r=0;r<10;r++) efr[r]=ef[r];
    float lg = d;
    #pragma unroll
    for(int r=0;r<10;r++) lg = fmaf(efr[r], QW[r], lg);
    lg *= 0.17677669529663687f;
    float mn = fmaxf(m, lg);
    float f = expf(m - mn);
    float w = expf(lg - mn);
    float2 vv = ldbf2(&qkvs[(size_t)s*512 + 256 + c0]);
    a0 = a0*f + w*vv.x;
    a1 = a1*f + w*vv.y;
    ssum = ssum*f + w;
    #pragma unroll
    for(int r=0;r<10;r++) S[r] = S[r]*f + w*efr[r];
    m = mn;
  }
  float ea0=0.f, ea1=0.f;
  #pragma unroll
  for(int r=0;r<10;r++){
    ea0 = fmaf(S[r], WeL[r*HID+c0],   ea0);
    ea1 = fmaf(S[r], WeL[r*HID+c0+1], ea1);
  }
  float inv = (hi>lo)? 1.f/ssum : 0.f;
  att[(size_t)n*HID+c0]   = (a0+ea0)*inv;
  att[(size_t)n*HID+c0+1] = (a1+ea1)*inv;
}

// ---------------- beta-gate + residual + softplus + LN (wave per node) ----------------
__global__ void combine_ln(const float* __restrict__ att, const __hip_bfloat16* __restrict__ qkvs,
                           const __hip_bfloat16* __restrict__ hn, const float* __restrict__ Wb,
                           const float* __restrict__ g, const float* __restrict__ b,
                           __hip_bfloat16* __restrict__ hn2, int N){
  int n = blockIdx.x*4 + (threadIdx.x>>6);
  if(n>=N) return;
  int lane = threadIdx.x&63;
  int c = 2*lane;
  float2 o  = *(const float2*)&att[(size_t)n*HID+c];
  float2 xr = ldbf2(&qkvs[(size_t)n*512 + 384 + c]);
  float bl = o.x*Wb[c] + o.y*Wb[c+1]
           + xr.x*Wb[HID+c] + xr.y*Wb[HID+c+1]
           + (o.x-xr.x)*Wb[2*HID+c] + (o.y-xr.y)*Wb[2*HID+c+1];
  bl = wsum64(bl);
  float beta = sigm_(bl);
  float u0 = beta*xr.x + (1.f-beta)*o.x;
  float u1 = beta*xr.y + (1.f-beta)*o.y;
  float2 hnv = ldbf2(&hn[(size_t)n*HID+c]);
  float h0 = hnv.x + sp_(u0);
  float h1 = hnv.y + sp_(u1);
  float s1 = wsum64(h0+h1);
  float s2 = wsum64(h0*h0+h1*h1);
  float mu = s1*(1.f/HID);
  float var = s2*(1.f/HID)-mu*mu;
  float rs = rsqrtf(var+1e-5f);
  __hip_bfloat162 outv;
  outv.x = __float2bfloat16((h0-mu)*rs*g[c]+b[c]);
  outv.y = __float2bfloat16((h1-mu)*rs*g[c+1]+b[c+1]);
  *(__hip_bfloat162*)&hn2[(size_t)n*HID+c] = outv;
}

// ---------------- pooling + output head (block per graph) ----------------
__global__ void pool_head(const float* __restrict__ h, const int* __restrict__ batch,
                          const float* __restrict__ Wo1, const float* __restrict__ bo1,
                          const float* __restrict__ Wo2, const float* __restrict__ bo2,
                          float* __restrict__ out, int N){
  int gid = blockIdx.x;
  int t = threadIdx.x;  // 128 threads
  int lo = lb_(batch, N, gid), hi = lb_(batch, N, gid+1);
  __shared__ float pl[128];
  __shared__ float red[128];
  float s = 0.f;
  for(int i=lo;i<hi;i++) s += h[(size_t)i*HID + t];
  pl[t] = s;
  __syncthreads();
  float acc = bo1[t];
  for(int c=0;c<128;c++) acc = fmaf(pl[c], Wo1[c*HID+t], acc);
  red[t] = sp_(acc)*Wo2[t];
  __syncthreads();
  for(int off=64;off>0;off>>=1){
    if(t<off) red[t]+=red[t+off];
    __syncthreads();
  }
  if(t==0) out[gid] = red[0] + bo2[0];
}

extern "C" void kernel_launch(void* const* d_in, const int* in_sizes, int n_in,
                              void* d_out, int out_size, void* d_ws, size_t ws_size,
                              hipStream_t stream){
  const float* h_in = (const float*)d_in[0];
  const float* pos  = (const float*)d_in[1];
  const float* ew   = (const float*)d_in[2];
  const float* Wq = (const float*)d_in[3];  const float* bq = (const float*)d_in[4];
  const float* Wk = (const float*)d_in[5];  const float* bk = (const float*)d_in[6];
  const float* Wv = (const float*)d_in[7];  const float* bv = (const float*)d_in[8];
  const float* We = (const float*)d_in[9];
  const float* Wsk= (const float*)d_in[10]; const float* bsk=(const float*)d_in[11];
  const float* Wbeta=(const float*)d_in[12];
  const float* W1=(const float*)d_in[13]; const float* b1=(const float*)d_in[14];
  const float* W2=(const float*)d_in[15]; const float* b2=(const float*)d_in[16];
  const float* W3=(const float*)d_in[17]; const float* b3=(const float*)d_in[18];
  const float* lng=(const float*)d_in[19]; const float* lnb=(const float*)d_in[20];
  const float* Wo1=(const float*)d_in[21]; const float* bo1=(const float*)d_in[22];
  const float* Wo2=(const float*)d_in[23]; const float* bo2=(const float*)d_in[24];
  const int* ei    = (const int*)d_in[25];
  const int* batch = (const int*)d_in[26];
  int N = in_sizes[0]/HID;
  int E = in_sizes[2];
  int G = out_size;
  float* out = (float*)d_out;

  char* ws = (char*)d_ws;
  size_t off=0;
  auto alloc=[&](size_t bytes)->char*{
    char* p = ws + off;
    off = (off + bytes + 255) & ~(size_t)255;
    return p;
  };
  float* efeat =(float*)alloc((size_t)E*10*4);
  int* counts  =(int*)  alloc((size_t)N*4);
  int* counts2 =(int*)  alloc((size_t)N*4);
  int* rowst   =(int*)  alloc((size_t)(N+1)*4);
  int* tmp     =(int*)  alloc((size_t)N*4);
  int* bsums   =(int*)  alloc(256*4);
  int* boffs   =(int*)  alloc(256*4);
  int* csr     =(int*)  alloc((size_t)E*4);
  __hip_bfloat16* hn   =(__hip_bfloat16*)alloc((size_t)N*HID*2);
  __hip_bfloat16* hn2  =(__hip_bfloat16*)alloc((size_t)N*HID*2);
  __hip_bfloat16* qkvs =(__hip_bfloat16*)alloc((size_t)N*512*2);
  __hip_bfloat16* f1   =(__hip_bfloat16*)alloc((size_t)N*HID*2);
  __hip_bfloat16* f2   =(__hip_bfloat16*)alloc((size_t)N*HID*2);
  float* att   =(float*)alloc((size_t)N*HID*4);
  float* hcur  =(float*)alloc((size_t)N*HID*4);
  __hip_bfloat16* Wqkvs_t =(__hip_bfloat16*)alloc((size_t)NLAYER*512*128*2);
  __hip_bfloat16* Wffn_t  =(__hip_bfloat16*)alloc((size_t)NLAYER*3*128*128*2);
  float* bqkvs =(float*)alloc((size_t)NLAYER*512*4);

  int ebl = (E+255)/256;
  int nb  = (N+255)/256;
  int nwb = (N+3)/4;
  int nrb = (N+127)/128;
  dim3 gq(4, nrb);   // qkvs: 512 cols -> 8 blocks of 64... (set below)
  dim3 gqkvs(8, nrb);
  dim3 gffn(2, nrb);

  edge_prep<<<ebl,256,0,stream>>>(pos,ew,ei,efeat,E);
  hipMemsetAsync(counts, 0, (size_t)N*4, stream);
  hipMemsetAsync(counts2,0, (size_t)N*4, stream);
  csr_count<<<ebl,256,0,stream>>>(ei,counts,E);
  scan1<<<nb,256,0,stream>>>(counts,tmp,bsums,N);
  scan2<<<1,256,0,stream>>>(bsums,boffs,nb);
  finalize_rs<<<nb,256,0,stream>>>(tmp,boffs,rowst,N);
  csr_scatter<<<ebl,256,0,stream>>>(ei,rowst,counts2,csr,E);
  {
    int tot = NLAYER*512*128 + NLAYER*3*128*128 + NLAYER*512;
    pack_w<<<(tot+255)/256,256,0,stream>>>(Wq,Wk,Wv,Wsk,bq,bk,bv,bsk,W1,W2,W3,
                                           Wqkvs_t,bqkvs,Wffn_t);
  }

  const float* hprev = h_in;
  for(int l=0;l<NLAYER;l++){
    const float* We_l = We + (size_t)l*(KRBF+1)*HID;
    const float* Wb_l = Wbeta + (size_t)l*3*HID;
    const float* b1_l = b1 + (size_t)l*HID;
    const float* b2_l = b2 + (size_t)l*HID;
    const float* b3_l = b3 + (size_t)l*HID;

    ln_node<<<nwb,256,0,stream>>>(hprev,lng,lnb,hn,N);
    gemm_mfma<<<gqkvs,256,0,stream>>>(hn, Wqkvs_t + (size_t)l*512*128, bqkvs + l*512,
                                      nullptr, qkvs, N, 512, 0, 0);
    attn_fused<<<nwb,256,0,stream>>>(qkvs,efeat,We_l,ei,rowst,csr,att,N);
    combine_ln<<<nwb,256,0,stream>>>(att,qkvs,hn,Wb_l,lng,lnb,hn2,N);
    gemm_mfma<<<gffn,256,0,stream>>>(hn2, Wffn_t + (size_t)(l*3+0)*16384, b1_l,
                                     nullptr, f1, N, 128, 1, 0);
    gemm_mfma<<<gffn,256,0,stream>>>(f1,  Wffn_t + (size_t)(l*3+1)*16384, b2_l,
                                     nullptr, f2, N, 128, 1, 0);
    gemm_mfma<<<gffn,256,0,stream>>>(f2,  Wffn_t + (size_t)(l*3+2)*16384, b3_l,
                                     hn2, hcur, N, 128, 1, 1);
    hprev = hcur;
  }
  pool_head<<<G,128,0,stream>>>(hcur,batch,Wo1,bo1,Wo2,bo2,out,N);
}

// Round 3
// 1107.002 us; speedup vs baseline: 1.7894x; 1.1074x over previous
//
#include <hip/hip_runtime.h>
#include <hip/hip_bf16.h>
#include <math.h>

#define HID 128
#define KRBF 9
#define NLAYER 3
#define QSTR 560   // qkvs row stride: q|k|v|skip (512) + QW (40) + pad (8)
#define QWCOLS 576 // packed weight col count (multiple of 64)

typedef __attribute__((ext_vector_type(8))) short bf16x8;
typedef __attribute__((ext_vector_type(4))) float f32x4;

__device__ __forceinline__ float sp_(float x){ return fmaxf(x,0.f) + log1pf(expf(-fabsf(x))); }
__device__ __forceinline__ float sigm_(float x){ return 1.f/(1.f+expf(-x)); }
__device__ __forceinline__ float b2f(short s){
  union{unsigned u; float f;} x; x.u = ((unsigned)(unsigned short)s)<<16; return x.f;
}
__device__ __forceinline__ float wsum64(float v){
  #pragma unroll
  for(int m=1;m<64;m<<=1) v += __shfl_xor(v,m,64);
  return v;
}
__device__ __forceinline__ float2 ldbf2(const __hip_bfloat16* p){
  __hip_bfloat162 b = *(const __hip_bfloat162*)p;
  return make_float2(__bfloat162float(b.x), __bfloat162float(b.y));
}
__device__ __forceinline__ int lb_(const int* __restrict__ a, int n, int key){
  int lo=0, hi=n;
  while(lo<hi){ int mid=(lo+hi)>>1; if(a[mid]<key) lo=mid+1; else hi=mid; }
  return lo;
}

// ---------------- CSR counts ----------------
__global__ void count_dst(const int* __restrict__ ei, int* __restrict__ counts, int E){
  int e = blockIdx.x*256+threadIdx.x;
  if(e<E) atomicAdd(&counts[ei[E+e]],1);
}
__global__ void scan1(const int* __restrict__ counts, int* __restrict__ tmp,
                      int* __restrict__ bsums, int N){
  __shared__ int lds[256];
  int t = threadIdx.x; int idx = blockIdx.x*256+t;
  int v = (idx<N)? counts[idx]:0;
  lds[t]=v; __syncthreads();
  for(int off=1;off<256;off<<=1){
    int x = (t>=off)? lds[t-off]:0;
    __syncthreads();
    lds[t]+=x; __syncthreads();
  }
  if(idx<N) tmp[idx]=lds[t];
  if(t==255) bsums[blockIdx.x]=lds[255];
}
__global__ void scan2(const int* __restrict__ bsums, int* __restrict__ boffs, int nb){
  __shared__ int lds[256];
  int t=threadIdx.x;
  int v = (t<nb)? bsums[t]:0;
  lds[t]=v; __syncthreads();
  for(int off=1;off<256;off<<=1){
    int x=(t>=off)?lds[t-off]:0;
    __syncthreads();
    lds[t]+=x; __syncthreads();
  }
  if(t<nb) boffs[t] = lds[t]-v; // exclusive
}
__global__ void finalize_rs(const int* __restrict__ tmp, const int* __restrict__ boffs,
                            int* __restrict__ row_start, int N){
  int idx = blockIdx.x*256+threadIdx.x;
  if(idx<N) row_start[idx+1] = tmp[idx] + boffs[idx>>8];
  if(idx==0) row_start[0]=0;
}

// ---------------- edge features (sorted by dst) ----------------
__global__ void edge_prep(const float* __restrict__ pos, const float* __restrict__ ew,
                          const int* __restrict__ ei, const int* __restrict__ rowst,
                          int* __restrict__ counts2, float* __restrict__ efs,
                          int* __restrict__ esrc, int E){
  int e = blockIdx.x*256 + threadIdx.x;
  if(e>=E) return;
  int s = ei[e], d = ei[E+e];
  float dx = pos[d*3+0]-pos[s*3+0];
  float dy = pos[d*3+1]-pos[s*3+1];
  float dz = pos[d*3+2]-pos[s*3+2];
  float D = sqrtf(dx*dx+dy*dy+dz*dz);
  float x = D*0.1f;
  float cut = 0.f;
  if(x < 1.f){ float x3=x*x*x, x4=x3*x, x5=x4*x; cut = 1.f - 6.f*x5 + 15.f*x4 - 10.f*x3; }
  float ed = expf(-D);
  const double e10 = 4.5399929762484854e-05; // exp(-10)
  const float step  = (float)((e10 - 1.0)/8.0);
  const float width = (float)((4.5/(1.0-e10))*(4.5/(1.0-e10)));
  float r12[12];
  #pragma unroll
  for(int k=0;k<KRBF;k++){
    float c = 1.0f + k*step;
    float dd = ed - c;
    r12[k] = cut*expf(-width*dd*dd);
  }
  r12[9] = ew[e]; r12[10]=0.f; r12[11]=0.f;
  int p = rowst[d] + atomicAdd(&counts2[d],1);
  float* o = efs + (size_t)p*12;
  *(float4*)&o[0] = *(float4*)&r12[0];
  *(float4*)&o[4] = *(float4*)&r12[4];
  *(float4*)&o[8] = *(float4*)&r12[8];
  esrc[p] = s;
}

// ---------------- weight packing (fp32 -> bf16, [col][k]; QW cols fused) ----------------
__global__ void pack_w(const float* __restrict__ Wq, const float* __restrict__ Wk,
                       const float* __restrict__ Wv, const float* __restrict__ Wsk,
                       const float* __restrict__ bq, const float* __restrict__ bk,
                       const float* __restrict__ bv, const float* __restrict__ bsk,
                       const float* __restrict__ We,
                       const float* __restrict__ W1, const float* __restrict__ W2,
                       const float* __restrict__ W3,
                       __hip_bfloat16* __restrict__ Wqkvs, float* __restrict__ bqkvs,
                       __hip_bfloat16* __restrict__ Wffn){
  int idx = blockIdx.x*256 + threadIdx.x;
  const int QT = NLAYER*QWCOLS*128;
  const int FT = NLAYER*3*128*128;
  const int BT = NLAYER*QWCOLS;
  if(idx < QT){
    int l = idx / (QWCOLS*128);
    int rem = idx - l*(QWCOLS*128);
    int col = rem >> 7, k = rem & 127;
    float v;
    if(col < 512){
      const float* src = (col<128)?Wq:((col<256)?Wk:((col<384)?Wv:Wsk));
      v = src[(size_t)l*16384 + k*128 + (col&127)];
    } else if(col < 552){
      int j = col-512; int h=j/10; int r=j-10*h;
      const float* wq = Wq + (size_t)l*16384 + k*128;
      const float* we = We + (size_t)l*1280 + r*128;
      float acc=0.f;
      #pragma unroll 8
      for(int c=32*h;c<32*h+32;c++) acc = fmaf(wq[c], we[c], acc);
      v = acc;
    } else v = 0.f;
    Wqkvs[idx] = __float2bfloat16(v);
  } else if(idx < QT+FT){
    int j = idx - QT;
    int k = j & 127; int n = (j>>7)&127; int f = (j>>14)%3; int l = j/(3*16384);
    const float* src = (f==0)?W1:((f==1)?W2:W3);
    Wffn[j] = __float2bfloat16(src[(size_t)l*16384 + k*128 + n]);
  } else if(idx < QT+FT+BT){
    int j = idx - QT - FT;
    int l = j/QWCOLS; int col = j - l*QWCOLS;
    float v;
    if(col<512){
      const float* src = (col<128)?bq:((col<256)?bk:((col<384)?bv:bsk));
      v = src[l*128 + (col&127)];
    } else if(col<552){
      int jj=col-512; int h=jj/10; int r=jj-10*h;
      const float* bqp = bq + l*128;
      const float* we = We + (size_t)l*1280 + r*128;
      float acc=0.f;
      for(int c=32*h;c<32*h+32;c++) acc = fmaf(bqp[c], we[c], acc);
      v = acc;
    } else v = 0.f;
    bqkvs[j] = v;
  }
}

// ---------------- LayerNorm (wave per node) fp32 -> bf16 ----------------
__global__ void ln_node(const float* __restrict__ h, const float* __restrict__ g,
                        const float* __restrict__ b, __hip_bfloat16* __restrict__ hn, int N){
  int n = blockIdx.x*4 + (threadIdx.x>>6);
  if(n>=N) return;
  int lane = threadIdx.x & 63;
  int c = 2*lane;
  float2 v = *(const float2*)&h[(size_t)n*HID + c];
  float s1 = wsum64(v.x+v.y);
  float s2 = wsum64(v.x*v.x+v.y*v.y);
  float mu = s1*(1.f/HID);
  float var = s2*(1.f/HID) - mu*mu;
  float rs = rsqrtf(var + 1e-5f);
  __hip_bfloat162 o;
  o.x = __float2bfloat16((v.x-mu)*rs*g[c]   + b[c]);
  o.y = __float2bfloat16((v.y-mu)*rs*g[c+1] + b[c+1]);
  *(__hip_bfloat162*)&hn[(size_t)n*HID + c] = o;
}

// ---------------- MFMA bf16 GEMM: out[N x ncols] = A[N x 128] @ Wt^T ----------------
__global__ __launch_bounds__(256) void gemm_mfma(
    const __hip_bfloat16* __restrict__ A, const __hip_bfloat16* __restrict__ Wt,
    const float* __restrict__ bias, const __hip_bfloat16* __restrict__ res,
    void* __restrict__ outp, int N, int ostride, int ncols, int act, int out_f32){
  __shared__ __hip_bfloat16 As[128][136];
  __shared__ __hip_bfloat16 Ws[64][136];
  int row0 = blockIdx.y*128;
  int col0 = blockIdx.x*64;
  int tid = threadIdx.x;
  {
    int chunk = tid&15; int rbase = tid>>4;
    #pragma unroll
    for(int i=0;i<8;i++){
      int r = rbase + 16*i;
      int row = row0 + r;
      float4 v = make_float4(0.f,0.f,0.f,0.f);
      if(row < N) v = *(const float4*)&A[(size_t)row*128 + chunk*8];
      *(float4*)&As[r][chunk*8] = v;
    }
    #pragma unroll
    for(int i=0;i<4;i++){
      int c = rbase + 16*i;
      *(float4*)&Ws[c][chunk*8] = *(const float4*)&Wt[(size_t)(col0+c)*128 + chunk*8];
    }
  }
  __syncthreads();
  int wave = tid>>6, lane = tid&63;
  int m0 = wave*32;
  int ql = lane>>4;
  int il = lane&15;
  f32x4 acc[2][4];
  #pragma unroll
  for(int mi=0;mi<2;mi++)
    #pragma unroll
    for(int nj=0;nj<4;nj++)
      acc[mi][nj] = (f32x4){0.f,0.f,0.f,0.f};
  #pragma unroll
  for(int kk=0;kk<128;kk+=32){
    bf16x8 a0 = *(bf16x8*)&As[m0+il][kk+ql*8];
    bf16x8 a1 = *(bf16x8*)&As[m0+16+il][kk+ql*8];
    bf16x8 bb[4];
    #pragma unroll
    for(int nj=0;nj<4;nj++) bb[nj] = *(bf16x8*)&Ws[nj*16+il][kk+ql*8];
    #pragma unroll
    for(int nj=0;nj<4;nj++){
      acc[0][nj] = __builtin_amdgcn_mfma_f32_16x16x32_bf16(a0, bb[nj], acc[0][nj], 0,0,0);
      acc[1][nj] = __builtin_amdgcn_mfma_f32_16x16x32_bf16(a1, bb[nj], acc[1][nj], 0,0,0);
    }
  }
  #pragma unroll
  for(int mi=0;mi<2;mi++){
    int rowb = row0 + m0 + mi*16 + ql*4;
    #pragma unroll
    for(int r=0;r<4;r++){
      int rr = rowb + r;
      if(rr >= N) continue;
      #pragma unroll
      for(int nj=0;nj<4;nj++){
        int cg = col0 + nj*16 + il;
        if(cg >= ncols) continue;
        float t = acc[mi][nj][r] + bias[cg];
        if(act) t = sp_(t);
        if(res) t += __bfloat162float(res[(size_t)rr*128 + cg]);
        if(out_f32) ((float*)outp)[(size_t)rr*ostride + cg] = t;
        else ((__hip_bfloat16*)outp)[(size_t)rr*ostride + cg] = __float2bfloat16(t);
      }
    }
  }
}

// ---------------- fused attention v2: 4 edges/wave, 16 lanes/edge, 8 ch/lane ----------------
// no-max softmax (logits ~O(1), clamp at 80 guards overflow); QW precomputed by GEMM.
__global__ __launch_bounds__(256) void attn_fused2(
    const __hip_bfloat16* __restrict__ qkvs, const float* __restrict__ efs,
    const int* __restrict__ esrc, const float* __restrict__ WeL,
    const int* __restrict__ rowst, float* __restrict__ att, int N){
  int n = blockIdx.x*4 + (threadIdx.x>>6);
  if(n>=N) return;
  int lane = threadIdx.x & 63;
  int eg = lane>>4, sl = lane&15;
  int c8 = sl*8, hd = sl>>2;
  const __hip_bfloat16* rowq = qkvs + (size_t)n*QSTR;
  float q8[8];
  {
    bf16x8 qv = *(const bf16x8*)&rowq[c8];
    #pragma unroll
    for(int j=0;j<8;j++) q8[j] = b2f(qv[j]);
  }
  float QW[10];
  #pragma unroll
  for(int r=0;r<10;r++) QW[r] = __bfloat162float(rowq[512 + hd*10 + r]);
  int lo = rowst[n], hi = rowst[n+1];
  float ssum = 0.f;
  float a8[8]; float S[10];
  #pragma unroll
  for(int j=0;j<8;j++) a8[j]=0.f;
  #pragma unroll
  for(int r=0;r<10;r++) S[r]=0.f;
  for(int i=lo+eg; i<hi; i+=4){
    int s = esrc[i];
    const __hip_bfloat16* rs_ = qkvs + (size_t)s*QSTR;
    bf16x8 kv = *(const bf16x8*)&rs_[128 + c8];
    bf16x8 vv = *(const bf16x8*)&rs_[256 + c8];
    const float* ef = efs + (size_t)i*12;
    float4 e0 = *(const float4*)&ef[0];
    float4 e1 = *(const float4*)&ef[4];
    float2 e2 = *(const float2*)&ef[8];
    float d = 0.f;
    #pragma unroll
    for(int j=0;j<8;j++) d = fmaf(q8[j], b2f(kv[j]), d);
    d += __shfl_xor(d,1,64); d += __shfl_xor(d,2,64);
    float lg = d;
    lg = fmaf(e0.x,QW[0],lg); lg = fmaf(e0.y,QW[1],lg);
    lg = fmaf(e0.z,QW[2],lg); lg = fmaf(e0.w,QW[3],lg);
    lg = fmaf(e1.x,QW[4],lg); lg = fmaf(e1.y,QW[5],lg);
    lg = fmaf(e1.z,QW[6],lg); lg = fmaf(e1.w,QW[7],lg);
    lg = fmaf(e2.x,QW[8],lg); lg = fmaf(e2.y,QW[9],lg);
    lg *= 0.17677669529663687f;
    lg = fminf(lg, 80.f);
    float w = __expf(lg);
    ssum += w;
    #pragma unroll
    for(int j=0;j<8;j++) a8[j] = fmaf(w, b2f(vv[j]), a8[j]);
    S[0]=fmaf(w,e0.x,S[0]); S[1]=fmaf(w,e0.y,S[1]); S[2]=fmaf(w,e0.z,S[2]);
    S[3]=fmaf(w,e0.w,S[3]); S[4]=fmaf(w,e1.x,S[4]); S[5]=fmaf(w,e1.y,S[5]);
    S[6]=fmaf(w,e1.z,S[6]); S[7]=fmaf(w,e1.w,S[7]); S[8]=fmaf(w,e2.x,S[8]);
    S[9]=fmaf(w,e2.y,S[9]);
  }
  #pragma unroll
  for(int m=16;m<64;m<<=1){
    ssum += __shfl_xor(ssum,m,64);
    #pragma unroll
    for(int j=0;j<8;j++) a8[j] += __shfl_xor(a8[j],m,64);
    #pragma unroll
    for(int r=0;r<10;r++) S[r] += __shfl_xor(S[r],m,64);
  }
  float inv = (hi>lo)? 1.f/ssum : 0.f;
  float o8[8];
  #pragma unroll
  for(int j=0;j<8;j++) o8[j]=a8[j];
  #pragma unroll
  for(int r=0;r<10;r++){
    float s=S[r];
    float4 wa = *(const float4*)&WeL[r*128+c8];
    float4 wb = *(const float4*)&WeL[r*128+c8+4];
    o8[0]=fmaf(s,wa.x,o8[0]); o8[1]=fmaf(s,wa.y,o8[1]);
    o8[2]=fmaf(s,wa.z,o8[2]); o8[3]=fmaf(s,wa.w,o8[3]);
    o8[4]=fmaf(s,wb.x,o8[4]); o8[5]=fmaf(s,wb.y,o8[5]);
    o8[6]=fmaf(s,wb.z,o8[6]); o8[7]=fmaf(s,wb.w,o8[7]);
  }
  if(eg==0){
    float4 v0 = make_float4(o8[0]*inv, o8[1]*inv, o8[2]*inv, o8[3]*inv);
    float4 v1 = make_float4(o8[4]*inv, o8[5]*inv, o8[6]*inv, o8[7]*inv);
    *(float4*)&att[(size_t)n*128 + c8]     = v0;
    *(float4*)&att[(size_t)n*128 + c8 + 4] = v1;
  }
}

// ---------------- beta-gate + residual + softplus + LN (wave per node) ----------------
__global__ void combine_ln(const float* __restrict__ att, const __hip_bfloat16* __restrict__ qkvs,
                           const __hip_bfloat16* __restrict__ hn, const float* __restrict__ Wb,
                           const float* __restrict__ g, const float* __restrict__ b,
                           __hip_bfloat16* __restrict__ hn2, int N){
  int n = blockIdx.x*4 + (threadIdx.x>>6);
  if(n>=N) return;
  int lane = threadIdx.x&63;
  int c = 2*lane;
  float2 o  = *(const float2*)&att[(size_t)n*HID+c];
  float2 xr = ldbf2(&qkvs[(size_t)n*QSTR + 384 + c]);
  float bl = o.x*Wb[c] + o.y*Wb[c+1]
           + xr.x*Wb[HID+c] + xr.y*Wb[HID+c+1]
           + (o.x-xr.x)*Wb[2*HID+c] + (o.y-xr.y)*Wb[2*HID+c+1];
  bl = wsum64(bl);
  float beta = sigm_(bl);
  float u0 = beta*xr.x + (1.f-beta)*o.x;
  float u1 = beta*xr.y + (1.f-beta)*o.y;
  float2 hnv = ldbf2(&hn[(size_t)n*HID+c]);
  float h0 = hnv.x + sp_(u0);
  float h1 = hnv.y + sp_(u1);
  float s1 = wsum64(h0+h1);
  float s2 = wsum64(h0*h0+h1*h1);
  float mu = s1*(1.f/HID);
  float var = s2*(1.f/HID)-mu*mu;
  float rs = rsqrtf(var+1e-5f);
  __hip_bfloat162 outv;
  outv.x = __float2bfloat16((h0-mu)*rs*g[c]+b[c]);
  outv.y = __float2bfloat16((h1-mu)*rs*g[c+1]+b[c+1]);
  *(__hip_bfloat162*)&hn2[(size_t)n*HID+c] = outv;
}

// ---------------- pooling + output head (block per graph) ----------------
__global__ void pool_head(const float* __restrict__ h, const int* __restrict__ batch,
                          const float* __restrict__ Wo1, const float* __restrict__ bo1,
                          const float* __restrict__ Wo2, const float* __restrict__ bo2,
                          float* __restrict__ out, int N){
  int gid = blockIdx.x;
  int t = threadIdx.x;  // 128 threads
  int lo = lb_(batch, N, gid), hi = lb_(batch, N, gid+1);
  __shared__ float pl[128];
  __shared__ float red[128];
  float s = 0.f;
  for(int i=lo;i<hi;i++) s += h[(size_t)i*HID + t];
  pl[t] = s;
  __syncthreads();
  float acc = bo1[t];
  for(int c=0;c<128;c++) acc = fmaf(pl[c], Wo1[c*HID+t], acc);
  red[t] = sp_(acc)*Wo2[t];
  __syncthreads();
  for(int off=64;off>0;off>>=1){
    if(t<off) red[t]+=red[t+off];
    __syncthreads();
  }
  if(t==0) out[gid] = red[0] + bo2[0];
}

extern "C" void kernel_launch(void* const* d_in, const int* in_sizes, int n_in,
                              void* d_out, int out_size, void* d_ws, size_t ws_size,
                              hipStream_t stream){
  const float* h_in = (const float*)d_in[0];
  const float* pos  = (const float*)d_in[1];
  const float* ew   = (const float*)d_in[2];
  const float* Wq = (const float*)d_in[3];  const float* bq = (const float*)d_in[4];
  const float* Wk = (const float*)d_in[5];  const float* bk = (const float*)d_in[6];
  const float* Wv = (const float*)d_in[7];  const float* bv = (const float*)d_in[8];
  const float* We = (const float*)d_in[9];
  const float* Wsk= (const float*)d_in[10]; const float* bsk=(const float*)d_in[11];
  const float* Wbeta=(const float*)d_in[12];
  const float* W1=(const float*)d_in[13]; const float* b1=(const float*)d_in[14];
  const float* W2=(const float*)d_in[15]; const float* b2=(const float*)d_in[16];
  const float* W3=(const float*)d_in[17]; const float* b3=(const float*)d_in[18];
  const float* lng=(const float*)d_in[19]; const float* lnb=(const float*)d_in[20];
  const float* Wo1=(const float*)d_in[21]; const float* bo1=(const float*)d_in[22];
  const float* Wo2=(const float*)d_in[23]; const float* bo2=(const float*)d_in[24];
  const int* ei    = (const int*)d_in[25];
  const int* batch = (const int*)d_in[26];
  int N = in_sizes[0]/HID;
  int E = in_sizes[2];
  int G = out_size;
  float* out = (float*)d_out;

  char* ws = (char*)d_ws;
  size_t off=0;
  auto alloc=[&](size_t bytes)->char*{
    char* p = ws + off;
    off = (off + bytes + 255) & ~(size_t)255;
    return p;
  };
  float* efs   =(float*)alloc((size_t)E*12*4);
  int* esrc    =(int*)  alloc((size_t)E*4);
  int* counts  =(int*)  alloc((size_t)N*4);
  int* counts2 =(int*)  alloc((size_t)N*4);
  int* rowst   =(int*)  alloc((size_t)(N+1)*4);
  int* tmp     =(int*)  alloc((size_t)N*4);
  int* bsums   =(int*)  alloc(256*4);
  int* boffs   =(int*)  alloc(256*4);
  __hip_bfloat16* hn   =(__hip_bfloat16*)alloc((size_t)N*HID*2);
  __hip_bfloat16* hn2  =(__hip_bfloat16*)alloc((size_t)N*HID*2);
  __hip_bfloat16* qkvs =(__hip_bfloat16*)alloc((size_t)N*QSTR*2);
  __hip_bfloat16* f1   =(__hip_bfloat16*)alloc((size_t)N*HID*2);
  __hip_bfloat16* f2   =(__hip_bfloat16*)alloc((size_t)N*HID*2);
  float* att   =(float*)alloc((size_t)N*HID*4);
  float* hcur  =(float*)alloc((size_t)N*HID*4);
  __hip_bfloat16* Wqkvs_t =(__hip_bfloat16*)alloc((size_t)NLAYER*QWCOLS*128*2);
  __hip_bfloat16* Wffn_t  =(__hip_bfloat16*)alloc((size_t)NLAYER*3*128*128*2);
  float* bqkvs =(float*)alloc((size_t)NLAYER*QWCOLS*4);

  int ebl = (E+255)/256;
  int nb  = (N+255)/256;
  int nwb = (N+3)/4;
  int nrb = (N+127)/128;
  dim3 gqkvs(9, nrb);
  dim3 gffn(2, nrb);

  hipMemsetAsync(counts, 0, (size_t)N*4, stream);
  hipMemsetAsync(counts2,0, (size_t)N*4, stream);
  count_dst<<<ebl,256,0,stream>>>(ei,counts,E);
  scan1<<<nb,256,0,stream>>>(counts,tmp,bsums,N);
  scan2<<<1,256,0,stream>>>(bsums,boffs,nb);
  finalize_rs<<<nb,256,0,stream>>>(tmp,boffs,rowst,N);
  edge_prep<<<ebl,256,0,stream>>>(pos,ew,ei,rowst,counts2,efs,esrc,E);
  {
    int tot = NLAYER*QWCOLS*128 + NLAYER*3*128*128 + NLAYER*QWCOLS;
    pack_w<<<(tot+255)/256,256,0,stream>>>(Wq,Wk,Wv,Wsk,bq,bk,bv,bsk,We,W1,W2,W3,
                                           Wqkvs_t,bqkvs,Wffn_t);
  }

  const float* hprev = h_in;
  for(int l=0;l<NLAYER;l++){
    const float* We_l = We + (size_t)l*(KRBF+1)*HID;
    const float* Wb_l = Wbeta + (size_t)l*3*HID;
    const float* b1_l = b1 + (size_t)l*HID;
    const float* b2_l = b2 + (size_t)l*HID;
    const float* b3_l = b3 + (size_t)l*HID;

    ln_node<<<nwb,256,0,stream>>>(hprev,lng,lnb,hn,N);
    gemm_mfma<<<gqkvs,256,0,stream>>>(hn, Wqkvs_t + (size_t)l*QWCOLS*128, bqkvs + l*QWCOLS,
                                      nullptr, qkvs, N, QSTR, QSTR, 0, 0);
    attn_fused2<<<nwb,256,0,stream>>>(qkvs,efs,esrc,We_l,rowst,att,N);
    combine_ln<<<nwb,256,0,stream>>>(att,qkvs,hn,Wb_l,lng,lnb,hn2,N);
    gemm_mfma<<<gffn,256,0,stream>>>(hn2, Wffn_t + (size_t)(l*3+0)*16384, b1_l,
                                     nullptr, f1, N, 128, 128, 1, 0);
    gemm_mfma<<<gffn,256,0,stream>>>(f1,  Wffn_t + (size_t)(l*3+1)*16384, b2_l,
                                     nullptr, f2, N, 128, 128, 1, 0);
    gemm_mfma<<<gffn,256,0,stream>>>(f2,  Wffn_t + (size_t)(l*3+2)*16384, b3_l,
                                     hn2, hcur, N, 128, 128, 1, 1);
    hprev = hcur;
  }
  pool_head<<<G,128,0,stream>>>(hcur,batch,Wo1,bo1,Wo2,bo2,out,N);
}

// Round 4
// 1055.410 us; speedup vs baseline: 1.8769x; 1.0489x over previous
//
#include <hip/hip_runtime.h>
#include <hip/hip_bf16.h>
#include <math.h>

#define HID 128
#define KRBF 9
#define NLAYER 3
#define QSSTR 320   // qs row: q(128) | skip(128) | QW(40) | pad(24)
#define KVSTR 256   // kv row: k(128) | v(128)  -> 512B aligned
#define QWCOLS 576  // packed qkvs weight cols: q|k|v|skip (512) + QW(40) + pad(24)

typedef __attribute__((ext_vector_type(8))) short bf16x8;
typedef __attribute__((ext_vector_type(4))) float f32x4;

__device__ __forceinline__ float sp_(float x){ return fmaxf(x,0.f) + log1pf(expf(-fabsf(x))); }
__device__ __forceinline__ float sigm_(float x){ return 1.f/(1.f+expf(-x)); }
__device__ __forceinline__ float b2f(short s){
  union{unsigned u; float f;} x; x.u = ((unsigned)(unsigned short)s)<<16; return x.f;
}
__device__ __forceinline__ float wsum64(float v){
  #pragma unroll
  for(int m=1;m<64;m<<=1) v += __shfl_xor(v,m,64);
  return v;
}
__device__ __forceinline__ float wsum16(float v){
  #pragma unroll
  for(int m=1;m<16;m<<=1) v += __shfl_xor(v,m,64);
  return v;
}
__device__ __forceinline__ float2 ldbf2(const __hip_bfloat16* p){
  __hip_bfloat162 b = *(const __hip_bfloat162*)p;
  return make_float2(__bfloat162float(b.x), __bfloat162float(b.y));
}
__device__ __forceinline__ int lb_(const int* __restrict__ a, int n, int key){
  int lo=0, hi=n;
  while(lo<hi){ int mid=(lo+hi)>>1; if(a[mid]<key) lo=mid+1; else hi=mid; }
  return lo;
}

// ---------------- CSR counts ----------------
__global__ void count_dst(const int* __restrict__ ei, int* __restrict__ counts, int E){
  int e = blockIdx.x*256+threadIdx.x;
  if(e<E) atomicAdd(&counts[ei[E+e]],1);
}
__global__ void scan1(const int* __restrict__ counts, int* __restrict__ tmp,
                      int* __restrict__ bsums, int N){
  __shared__ int lds[256];
  int t = threadIdx.x; int idx = blockIdx.x*256+t;
  int v = (idx<N)? counts[idx]:0;
  lds[t]=v; __syncthreads();
  for(int off=1;off<256;off<<=1){
    int x = (t>=off)? lds[t-off]:0;
    __syncthreads();
    lds[t]+=x; __syncthreads();
  }
  if(idx<N) tmp[idx]=lds[t];
  if(t==255) bsums[blockIdx.x]=lds[255];
}
__global__ void scan2(const int* __restrict__ bsums, int* __restrict__ boffs, int nb){
  __shared__ int lds[256];
  int t=threadIdx.x;
  int v = (t<nb)? bsums[t]:0;
  lds[t]=v; __syncthreads();
  for(int off=1;off<256;off<<=1){
    int x=(t>=off)?lds[t-off]:0;
    __syncthreads();
    lds[t]+=x; __syncthreads();
  }
  if(t<nb) boffs[t] = lds[t]-v; // exclusive
}
__global__ void finalize_rs(const int* __restrict__ tmp, const int* __restrict__ boffs,
                            int* __restrict__ row_start, int N){
  int idx = blockIdx.x*256+threadIdx.x;
  if(idx<N) row_start[idx+1] = tmp[idx] + boffs[idx>>8];
  if(idx==0) row_start[0]=0;
}

// ---------------- edge features (sorted by dst) ----------------
__global__ void edge_prep(const float* __restrict__ pos, const float* __restrict__ ew,
                          const int* __restrict__ ei, const int* __restrict__ rowst,
                          int* __restrict__ counts2, float* __restrict__ efs,
                          int* __restrict__ esrc, int E){
  int e = blockIdx.x*256 + threadIdx.x;
  if(e>=E) return;
  int s = ei[e], d = ei[E+e];
  float dx = pos[d*3+0]-pos[s*3+0];
  float dy = pos[d*3+1]-pos[s*3+1];
  float dz = pos[d*3+2]-pos[s*3+2];
  float D = sqrtf(dx*dx+dy*dy+dz*dz);
  float x = D*0.1f;
  float cut = 0.f;
  if(x < 1.f){ float x3=x*x*x, x4=x3*x, x5=x4*x; cut = 1.f - 6.f*x5 + 15.f*x4 - 10.f*x3; }
  float ed = expf(-D);
  const double e10 = 4.5399929762484854e-05; // exp(-10)
  const float step  = (float)((e10 - 1.0)/8.0);
  const float width = (float)((4.5/(1.0-e10))*(4.5/(1.0-e10)));
  float r12[12];
  #pragma unroll
  for(int k=0;k<KRBF;k++){
    float c = 1.0f + k*step;
    float dd = ed - c;
    r12[k] = cut*expf(-width*dd*dd);
  }
  r12[9] = ew[e]; r12[10]=0.f; r12[11]=0.f;
  int p = rowst[d] + atomicAdd(&counts2[d],1);
  float* o = efs + (size_t)p*12;
  *(float4*)&o[0] = *(float4*)&r12[0];
  *(float4*)&o[4] = *(float4*)&r12[4];
  *(float4*)&o[8] = *(float4*)&r12[8];
  esrc[p] = s;
}

// ---------------- weight packing (fp32 -> bf16, [col][k]; QW cols fused) ----------------
__global__ void pack_w(const float* __restrict__ Wq, const float* __restrict__ Wk,
                       const float* __restrict__ Wv, const float* __restrict__ Wsk,
                       const float* __restrict__ bq, const float* __restrict__ bk,
                       const float* __restrict__ bv, const float* __restrict__ bsk,
                       const float* __restrict__ We,
                       const float* __restrict__ W1, const float* __restrict__ W2,
                       const float* __restrict__ W3,
                       __hip_bfloat16* __restrict__ Wqkvs, float* __restrict__ bqkvs,
                       __hip_bfloat16* __restrict__ Wffn){
  int idx = blockIdx.x*256 + threadIdx.x;
  const int QT = NLAYER*QWCOLS*128;
  const int FT = NLAYER*3*128*128;
  const int BT = NLAYER*QWCOLS;
  if(idx < QT){
    int l = idx / (QWCOLS*128);
    int rem = idx - l*(QWCOLS*128);
    int col = rem >> 7, k = rem & 127;
    float v;
    if(col < 512){
      const float* src = (col<128)?Wq:((col<256)?Wk:((col<384)?Wv:Wsk));
      v = src[(size_t)l*16384 + k*128 + (col&127)];
    } else if(col < 552){
      int j = col-512; int h=j/10; int r=j-10*h;
      const float* wq = Wq + (size_t)l*16384 + k*128;
      const float* we = We + (size_t)l*1280 + r*128;
      float acc=0.f;
      #pragma unroll 8
      for(int c=32*h;c<32*h+32;c++) acc = fmaf(wq[c], we[c], acc);
      v = acc;
    } else v = 0.f;
    Wqkvs[idx] = __float2bfloat16(v);
  } else if(idx < QT+FT){
    int j = idx - QT;
    int k = j & 127; int n = (j>>7)&127; int f = (j>>14)%3; int l = j/(3*16384);
    const float* src = (f==0)?W1:((f==1)?W2:W3);
    Wffn[j] = __float2bfloat16(src[(size_t)l*16384 + k*128 + n]);
  } else if(idx < QT+FT+BT){
    int j = idx - QT - FT;
    int l = j/QWCOLS; int col = j - l*QWCOLS;
    float v;
    if(col<512){
      const float* src = (col<128)?bq:((col<256)?bk:((col<384)?bv:bsk));
      v = src[l*128 + (col&127)];
    } else if(col<552){
      int jj=col-512; int h=jj/10; int r=jj-10*h;
      const float* bqp = bq + l*128;
      const float* we = We + (size_t)l*1280 + r*128;
      float acc=0.f;
      for(int c=32*h;c<32*h+32;c++) acc = fmaf(bqp[c], we[c], acc);
      v = acc;
    } else v = 0.f;
    bqkvs[j] = v;
  }
}

// ---------------- LayerNorm (wave per node) fp32 -> bf16 (layer 0 only) ----------------
__global__ void ln_node(const float* __restrict__ h, const float* __restrict__ g,
                        const float* __restrict__ b, __hip_bfloat16* __restrict__ hn, int N){
  int n = blockIdx.x*4 + (threadIdx.x>>6);
  if(n>=N) return;
  int lane = threadIdx.x & 63;
  int c = 2*lane;
  float2 v = *(const float2*)&h[(size_t)n*HID + c];
  float s1 = wsum64(v.x+v.y);
  float s2 = wsum64(v.x*v.x+v.y*v.y);
  float mu = s1*(1.f/HID);
  float var = s2*(1.f/HID) - mu*mu;
  float rs = rsqrtf(var + 1e-5f);
  __hip_bfloat162 o;
  o.x = __float2bfloat16((v.x-mu)*rs*g[c]   + b[c]);
  o.y = __float2bfloat16((v.y-mu)*rs*g[c+1] + b[c+1]);
  *(__hip_bfloat162*)&hn[(size_t)n*HID + c] = o;
}

// ---------------- MFMA bf16 GEMM 128x128 tile ----------------
// mode 0: qkvs — route cols to qs (q|skip|QW) and kvb (k|v), no act
// mode 1: softplus -> bf16 out0 (stride 128)
// mode 2: softplus + res(hn2) + row-LN -> out0 fp32 h, out1 bf16 hn
__global__ __launch_bounds__(256) void gemm_mfma(
    const __hip_bfloat16* __restrict__ A, const __hip_bfloat16* __restrict__ Wt,
    const float* __restrict__ bias, const __hip_bfloat16* __restrict__ res,
    void* __restrict__ out0, void* __restrict__ out1,
    const float* __restrict__ lng, const float* __restrict__ lnb,
    int N, int ncols, int mode){
  __shared__ __hip_bfloat16 As[128][136];
  __shared__ __hip_bfloat16 Ws[128][136];
  int row0 = blockIdx.y*128;
  int col0 = blockIdx.x*128;
  int tid = threadIdx.x;
  {
    int chunk = tid&15; int rbase = tid>>4;
    #pragma unroll
    for(int i=0;i<8;i++){
      int r = rbase + 16*i;
      int row = row0 + r;
      float4 v = make_float4(0.f,0.f,0.f,0.f);
      if(row < N) v = *(const float4*)&A[(size_t)row*128 + chunk*8];
      *(float4*)&As[r][chunk*8] = v;
    }
    #pragma unroll
    for(int i=0;i<8;i++){
      int c = rbase + 16*i;
      float4 v = make_float4(0.f,0.f,0.f,0.f);
      if(col0 + c < ncols) v = *(const float4*)&Wt[(size_t)(col0+c)*128 + chunk*8];
      *(float4*)&Ws[c][chunk*8] = v;
    }
  }
  __syncthreads();
  int lane = tid&63;
  int m0 = (tid>>6)*32;
  int ql = lane>>4;
  int il = lane&15;
  f32x4 acc[2][8];
  #pragma unroll
  for(int mi=0;mi<2;mi++)
    #pragma unroll
    for(int nj=0;nj<8;nj++)
      acc[mi][nj] = (f32x4){0.f,0.f,0.f,0.f};
  #pragma unroll
  for(int kk=0;kk<128;kk+=32){
    bf16x8 a0 = *(bf16x8*)&As[m0+il][kk+ql*8];
    bf16x8 a1 = *(bf16x8*)&As[m0+16+il][kk+ql*8];
    bf16x8 bb[8];
    #pragma unroll
    for(int nj=0;nj<8;nj++) bb[nj] = *(bf16x8*)&Ws[nj*16+il][kk+ql*8];
    #pragma unroll
    for(int nj=0;nj<8;nj++){
      acc[0][nj] = __builtin_amdgcn_mfma_f32_16x16x32_bf16(a0, bb[nj], acc[0][nj], 0,0,0);
      acc[1][nj] = __builtin_amdgcn_mfma_f32_16x16x32_bf16(a1, bb[nj], acc[1][nj], 0,0,0);
    }
  }
  if(mode==0){
    __hip_bfloat16* qs  = (__hip_bfloat16*)out0;
    __hip_bfloat16* kvb = (__hip_bfloat16*)out1;
    #pragma unroll
    for(int mi=0;mi<2;mi++){
      int rowb = row0 + m0 + mi*16 + ql*4;
      #pragma unroll
      for(int r=0;r<4;r++){
        int rr = rowb + r;
        if(rr >= N) continue;
        #pragma unroll
        for(int nj=0;nj<8;nj++){
          int cg = col0 + nj*16 + il;
          if(cg >= QWCOLS) continue;
          float t = acc[mi][nj][r] + bias[cg];
          __hip_bfloat16 bv = __float2bfloat16(t);
          if(cg < 128)      qs[(size_t)rr*QSSTR + cg] = bv;
          else if(cg < 384) kvb[(size_t)rr*KVSTR + (cg-128)] = bv;
          else if(cg < 512) qs[(size_t)rr*QSSTR + 128 + (cg-384)] = bv;
          else if(cg < 552) qs[(size_t)rr*QSSTR + 256 + (cg-512)] = bv;
        }
      }
    }
  } else if(mode==1){
    __hip_bfloat16* o = (__hip_bfloat16*)out0;
    #pragma unroll
    for(int mi=0;mi<2;mi++){
      int rowb = row0 + m0 + mi*16 + ql*4;
      #pragma unroll
      for(int r=0;r<4;r++){
        int rr = rowb + r;
        if(rr >= N) continue;
        #pragma unroll
        for(int nj=0;nj<8;nj++){
          int cg = nj*16 + il;
          o[(size_t)rr*128 + cg] = __float2bfloat16(sp_(acc[mi][nj][r] + bias[cg]));
        }
      }
    }
  } else {
    float* hout = (float*)out0;
    __hip_bfloat16* hnout = (__hip_bfloat16*)out1;
    #pragma unroll
    for(int mi=0;mi<2;mi++){
      int rowb = row0 + m0 + mi*16 + ql*4;
      float t[8][4];
      #pragma unroll
      for(int r=0;r<4;r++){
        int rr = rowb + r;
        bool ok = rr < N;
        #pragma unroll
        for(int nj=0;nj<8;nj++){
          int cg = nj*16 + il;
          float x = sp_(acc[mi][nj][r] + bias[cg]);
          float rv = ok ? __bfloat162float(res[(size_t)rr*128 + cg]) : 0.f;
          t[nj][r] = x + rv;
        }
      }
      #pragma unroll
      for(int r=0;r<4;r++){
        int rr = rowb + r;
        if(rr >= N) continue;   // uniform across the 16-lane shfl group
        float s1=0.f, s2=0.f;
        #pragma unroll
        for(int nj=0;nj<8;nj++){ float v=t[nj][r]; s1+=v; s2+=v*v; }
        s1 = wsum16(s1); s2 = wsum16(s2);
        float mu = s1*(1.f/128.f);
        float var = s2*(1.f/128.f) - mu*mu;
        float rs = rsqrtf(var + 1e-5f);
        #pragma unroll
        for(int nj=0;nj<8;nj++){
          int cg = nj*16 + il;
          float tv = t[nj][r];
          hout[(size_t)rr*128 + cg] = tv;
          hnout[(size_t)rr*128 + cg] = __float2bfloat16((tv-mu)*rs*lng[cg] + lnb[cg]);
        }
      }
    }
  }
}

// ---------------- fused attention: 4 edges/wave, 16 lanes/edge, 2-deep pipeline ----------------
__global__ __launch_bounds__(256) void attn_fused2(
    const __hip_bfloat16* __restrict__ qs, const __hip_bfloat16* __restrict__ kvb,
    const float* __restrict__ efs, const int* __restrict__ esrc,
    const float* __restrict__ WeL, const int* __restrict__ rowst,
    float* __restrict__ att, int N){
  int n = blockIdx.x*4 + (threadIdx.x>>6);
  if(n>=N) return;
  int lane = threadIdx.x & 63;
  int eg = lane>>4, sl = lane&15;
  int c8 = sl*8, hd = sl>>2;
  const __hip_bfloat16* rowq = qs + (size_t)n*QSSTR;
  float q8[8];
  {
    bf16x8 qv = *(const bf16x8*)&rowq[c8];
    #pragma unroll
    for(int j=0;j<8;j++) q8[j] = b2f(qv[j]);
  }
  float QW[10];
  #pragma unroll
  for(int r=0;r<10;r++) QW[r] = __bfloat162float(rowq[256 + hd*10 + r]);
  int lo = rowst[n], hi = rowst[n+1];
  float ssum = 0.f;
  float a8[8]; float S[10];
  #pragma unroll
  for(int j=0;j<8;j++) a8[j]=0.f;
  #pragma unroll
  for(int r=0;r<10;r++) S[r]=0.f;
  int i = lo + eg;
  if(i < hi){
    int s = esrc[i];
    const __hip_bfloat16* kr = kvb + (size_t)s*KVSTR;
    bf16x8 kc = *(const bf16x8*)&kr[c8];
    bf16x8 vc = *(const bf16x8*)&kr[128 + c8];
    const float* ef = efs + (size_t)i*12;
    float4 e0 = *(const float4*)&ef[0];
    float4 e1 = *(const float4*)&ef[4];
    float2 e2 = *(const float2*)&ef[8];
    while(true){
      int inext = i + 4;
      bool more = inext < hi;
      bf16x8 kn = kc, vn = vc;
      float4 f0 = e0, f1 = e1; float2 f2 = e2;
      if(more){
        int s2 = esrc[inext];
        const __hip_bfloat16* kr2 = kvb + (size_t)s2*KVSTR;
        kn = *(const bf16x8*)&kr2[c8];
        vn = *(const bf16x8*)&kr2[128 + c8];
        const float* ef2 = efs + (size_t)inext*12;
        f0 = *(const float4*)&ef2[0];
        f1 = *(const float4*)&ef2[4];
        f2 = *(const float2*)&ef2[8];
      }
      // compute current edge
      float d = 0.f;
      #pragma unroll
      for(int j=0;j<8;j++) d = fmaf(q8[j], b2f(kc[j]), d);
      d += __shfl_xor(d,1,64); d += __shfl_xor(d,2,64);   // per-head (quad) dot
      float lg = d;
      lg = fmaf(e0.x,QW[0],lg); lg = fmaf(e0.y,QW[1],lg);
      lg = fmaf(e0.z,QW[2],lg); lg = fmaf(e0.w,QW[3],lg);
      lg = fmaf(e1.x,QW[4],lg); lg = fmaf(e1.y,QW[5],lg);
      lg = fmaf(e1.z,QW[6],lg); lg = fmaf(e1.w,QW[7],lg);
      lg = fmaf(e2.x,QW[8],lg); lg = fmaf(e2.y,QW[9],lg);
      lg *= 0.17677669529663687f;
      lg = fminf(lg, 80.f);
      float w = __expf(lg);
      ssum += w;
      #pragma unroll
      for(int j=0;j<8;j++) a8[j] = fmaf(w, b2f(vc[j]), a8[j]);
      S[0]=fmaf(w,e0.x,S[0]); S[1]=fmaf(w,e0.y,S[1]); S[2]=fmaf(w,e0.z,S[2]);
      S[3]=fmaf(w,e0.w,S[3]); S[4]=fmaf(w,e1.x,S[4]); S[5]=fmaf(w,e1.y,S[5]);
      S[6]=fmaf(w,e1.z,S[6]); S[7]=fmaf(w,e1.w,S[7]); S[8]=fmaf(w,e2.x,S[8]);
      S[9]=fmaf(w,e2.y,S[9]);
      if(!more) break;
      kc = kn; vc = vn; e0 = f0; e1 = f1; e2 = f2;
      i = inext;
    }
  }
  #pragma unroll
  for(int m=16;m<64;m<<=1){
    ssum += __shfl_xor(ssum,m,64);
    #pragma unroll
    for(int j=0;j<8;j++) a8[j] += __shfl_xor(a8[j],m,64);
    #pragma unroll
    for(int r=0;r<10;r++) S[r] += __shfl_xor(S[r],m,64);
  }
  float inv = (hi>lo)? 1.f/ssum : 0.f;
  float o8[8];
  #pragma unroll
  for(int j=0;j<8;j++) o8[j]=a8[j];
  #pragma unroll
  for(int r=0;r<10;r++){
    float s=S[r];
    float4 wa = *(const float4*)&WeL[r*128+c8];
    float4 wb = *(const float4*)&WeL[r*128+c8+4];
    o8[0]=fmaf(s,wa.x,o8[0]); o8[1]=fmaf(s,wa.y,o8[1]);
    o8[2]=fmaf(s,wa.z,o8[2]); o8[3]=fmaf(s,wa.w,o8[3]);
    o8[4]=fmaf(s,wb.x,o8[4]); o8[5]=fmaf(s,wb.y,o8[5]);
    o8[6]=fmaf(s,wb.z,o8[6]); o8[7]=fmaf(s,wb.w,o8[7]);
  }
  if(eg==0){
    float4 v0 = make_float4(o8[0]*inv, o8[1]*inv, o8[2]*inv, o8[3]*inv);
    float4 v1 = make_float4(o8[4]*inv, o8[5]*inv, o8[6]*inv, o8[7]*inv);
    *(float4*)&att[(size_t)n*128 + c8]     = v0;
    *(float4*)&att[(size_t)n*128 + c8 + 4] = v1;
  }
}

// ---------------- beta-gate + residual + softplus + LN (wave per node) ----------------
__global__ void combine_ln(const float* __restrict__ att, const __hip_bfloat16* __restrict__ qs,
                           const __hip_bfloat16* __restrict__ hn, const float* __restrict__ Wb,
                           const float* __restrict__ g, const float* __restrict__ b,
                           __hip_bfloat16* __restrict__ hn2, int N){
  int n = blockIdx.x*4 + (threadIdx.x>>6);
  if(n>=N) return;
  int lane = threadIdx.x&63;
  int c = 2*lane;
  float2 o  = *(const float2*)&att[(size_t)n*HID+c];
  float2 xr = ldbf2(&qs[(size_t)n*QSSTR + 128 + c]);
  float bl = o.x*Wb[c] + o.y*Wb[c+1]
           + xr.x*Wb[HID+c] + xr.y*Wb[HID+c+1]
           + (o.x-xr.x)*Wb[2*HID+c] + (o.y-xr.y)*Wb[2*HID+c+1];
  bl = wsum64(bl);
  float beta = sigm_(bl);
  float u0 = beta*xr.x + (1.f-beta)*o.x;
  float u1 = beta*xr.y + (1.f-beta)*o.y;
  float2 hnv = ldbf2(&hn[(size_t)n*HID+c]);
  float h0 = hnv.x + sp_(u0);
  float h1 = hnv.y + sp_(u1);
  float s1 = wsum64(h0+h1);
  float s2 = wsum64(h0*h0+h1*h1);
  float mu = s1*(1.f/HID);
  float var = s2*(1.f/HID)-mu*mu;
  float rs = rsqrtf(var+1e-5f);
  __hip_bfloat162 outv;
  outv.x = __float2bfloat16((h0-mu)*rs*g[c]+b[c]);
  outv.y = __float2bfloat16((h1-mu)*rs*g[c+1]+b[c+1]);
  *(__hip_bfloat162*)&hn2[(size_t)n*HID+c] = outv;
}

// ---------------- pooling + output head (block per graph) ----------------
__global__ void pool_head(const float* __restrict__ h, const int* __restrict__ batch,
                          const float* __restrict__ Wo1, const float* __restrict__ bo1,
                          const float* __restrict__ Wo2, const float* __restrict__ bo2,
                          float* __restrict__ out, int N){
  int gid = blockIdx.x;
  int t = threadIdx.x;  // 128 threads
  int lo = lb_(batch, N, gid), hi = lb_(batch, N, gid+1);
  __shared__ float pl[128];
  __shared__ float red[128];
  float s = 0.f;
  for(int i=lo;i<hi;i++) s += h[(size_t)i*HID + t];
  pl[t] = s;
  __syncthreads();
  float acc = bo1[t];
  for(int c=0;c<128;c++) acc = fmaf(pl[c], Wo1[c*HID+t], acc);
  red[t] = sp_(acc)*Wo2[t];
  __syncthreads();
  for(int off=64;off>0;off>>=1){
    if(t<off) red[t]+=red[t+off];
    __syncthreads();
  }
  if(t==0) out[gid] = red[0] + bo2[0];
}

extern "C" void kernel_launch(void* const* d_in, const int* in_sizes, int n_in,
                              void* d_out, int out_size, void* d_ws, size_t ws_size,
                              hipStream_t stream){
  const float* h_in = (const float*)d_in[0];
  const float* pos  = (const float*)d_in[1];
  const float* ew   = (const float*)d_in[2];
  const float* Wq = (const float*)d_in[3];  const float* bq = (const float*)d_in[4];
  const float* Wk = (const float*)d_in[5];  const float* bk = (const float*)d_in[6];
  const float* Wv = (const float*)d_in[7];  const float* bv = (const float*)d_in[8];
  const float* We = (const float*)d_in[9];
  const float* Wsk= (const float*)d_in[10]; const float* bsk=(const float*)d_in[11];
  const float* Wbeta=(const float*)d_in[12];
  const float* W1=(const float*)d_in[13]; const float* b1=(const float*)d_in[14];
  const float* W2=(const float*)d_in[15]; const float* b2=(const float*)d_in[16];
  const float* W3=(const float*)d_in[17]; const float* b3=(const float*)d_in[18];
  const float* lng=(const float*)d_in[19]; const float* lnb=(const float*)d_in[20];
  const float* Wo1=(const float*)d_in[21]; const float* bo1=(const float*)d_in[22];
  const float* Wo2=(const float*)d_in[23]; const float* bo2=(const float*)d_in[24];
  const int* ei    = (const int*)d_in[25];
  const int* batch = (const int*)d_in[26];
  int N = in_sizes[0]/HID;
  int E = in_sizes[2];
  int G = out_size;
  float* out = (float*)d_out;

  char* ws = (char*)d_ws;
  size_t off=0;
  auto alloc=[&](size_t bytes)->char*{
    char* p = ws + off;
    off = (off + bytes + 255) & ~(size_t)255;
    return p;
  };
  float* efs   =(float*)alloc((size_t)E*12*4);
  int* esrc    =(int*)  alloc((size_t)E*4);
  int* counts  =(int*)  alloc((size_t)N*4);
  int* counts2 =(int*)  alloc((size_t)N*4);
  int* rowst   =(int*)  alloc((size_t)(N+1)*4);
  int* tmp     =(int*)  alloc((size_t)N*4);
  int* bsums   =(int*)  alloc(256*4);
  int* boffs   =(int*)  alloc(256*4);
  __hip_bfloat16* hn   =(__hip_bfloat16*)alloc((size_t)N*HID*2);
  __hip_bfloat16* hn2  =(__hip_bfloat16*)alloc((size_t)N*HID*2);
  __hip_bfloat16* qsb  =(__hip_bfloat16*)alloc((size_t)N*QSSTR*2);
  __hip_bfloat16* kvb  =(__hip_bfloat16*)alloc((size_t)N*KVSTR*2);
  __hip_bfloat16* f1   =(__hip_bfloat16*)alloc((size_t)N*HID*2);
  __hip_bfloat16* f2   =(__hip_bfloat16*)alloc((size_t)N*HID*2);
  float* att   =(float*)alloc((size_t)N*HID*4);
  float* hcur  =(float*)alloc((size_t)N*HID*4);
  __hip_bfloat16* Wqkvs_t =(__hip_bfloat16*)alloc((size_t)NLAYER*QWCOLS*128*2);
  __hip_bfloat16* Wffn_t  =(__hip_bfloat16*)alloc((size_t)NLAYER*3*128*128*2);
  float* bqkvs =(float*)alloc((size_t)NLAYER*QWCOLS*4);

  int ebl = (E+255)/256;
  int nb  = (N+255)/256;
  int nwb = (N+3)/4;
  int nrb = (N+127)/128;
  dim3 gqkvs((QWCOLS+127)/128, nrb);   // 5 x nrb
  dim3 gffn(1, nrb);

  hipMemsetAsync(counts, 0, (size_t)N*4, stream);
  hipMemsetAsync(counts2,0, (size_t)N*4, stream);
  count_dst<<<ebl,256,0,stream>>>(ei,counts,E);
  scan1<<<nb,256,0,stream>>>(counts,tmp,bsums,N);
  scan2<<<1,256,0,stream>>>(bsums,boffs,nb);
  finalize_rs<<<nb,256,0,stream>>>(tmp,boffs,rowst,N);
  edge_prep<<<ebl,256,0,stream>>>(pos,ew,ei,rowst,counts2,efs,esrc,E);
  {
    int tot = NLAYER*QWCOLS*128 + NLAYER*3*128*128 + NLAYER*QWCOLS;
    pack_w<<<(tot+255)/256,256,0,stream>>>(Wq,Wk,Wv,Wsk,bq,bk,bv,bsk,We,W1,W2,W3,
                                           Wqkvs_t,bqkvs,Wffn_t);
  }

  ln_node<<<nwb,256,0,stream>>>(h_in,lng,lnb,hn,N);
  for(int l=0;l<NLAYER;l++){
    const float* We_l = We + (size_t)l*(KRBF+1)*HID;
    const float* Wb_l = Wbeta + (size_t)l*3*HID;
    const float* b1_l = b1 + (size_t)l*HID;
    const float* b2_l = b2 + (size_t)l*HID;
    const float* b3_l = b3 + (size_t)l*HID;

    gemm_mfma<<<gqkvs,256,0,stream>>>(hn, Wqkvs_t + (size_t)l*QWCOLS*128, bqkvs + l*QWCOLS,
                                      nullptr, qsb, kvb, lng, lnb, N, QWCOLS, 0);
    attn_fused2<<<nwb,256,0,stream>>>(qsb,kvb,efs,esrc,We_l,rowst,att,N);
    combine_ln<<<nwb,256,0,stream>>>(att,qsb,hn,Wb_l,lng,lnb,hn2,N);
    gemm_mfma<<<gffn,256,0,stream>>>(hn2, Wffn_t + (size_t)(l*3+0)*16384, b1_l,
                                     nullptr, f1, nullptr, lng, lnb, N, 128, 1);
    gemm_mfma<<<gffn,256,0,stream>>>(f1,  Wffn_t + (size_t)(l*3+1)*16384, b2_l,
                                     nullptr, f2, nullptr, lng, lnb, N, 128, 1);
    // FFN3 + residual + LayerNorm fused: writes h (fp32) and hn for next layer (bf16)
    gemm_mfma<<<gffn,256,0,stream>>>(f2,  Wffn_t + (size_t)(l*3+2)*16384, b3_l,
                                     hn2, hcur, hn, lng, lnb, N, 128, 2);
  }
  pool_head<<<G,128,0,stream>>>(hcur,batch,Wo1,bo1,Wo2,bo2,out,N);
}

// Round 5
// 961.841 us; speedup vs baseline: 2.0595x; 1.0973x over previous
//
#include <hip/hip_runtime.h>
#include <hip/hip_bf16.h>
#include <math.h>

#define HID 128
#define KRBF 9
#define NLAYER 3
#define QSSTR 320   // qs row: q(128) | skip(128) | QW(40) | pad(24)
#define KVSTR 256   // kv row: k(128) | v(128)  -> 512B aligned
#define QWCOLS 640  // packed qkvs weight cols: 5 blocks of 128 (q|k|v|skip|QW+pad)

typedef __attribute__((ext_vector_type(8))) short bf16x8;
typedef __attribute__((ext_vector_type(4))) float f32x4;

__device__ __forceinline__ float sp_(float x){ return fmaxf(x,0.f) + log1pf(expf(-fabsf(x))); }
__device__ __forceinline__ float sigm_(float x){ return 1.f/(1.f+expf(-x)); }
__device__ __forceinline__ float b2f(short s){
  union{unsigned u; float f;} x; x.u = ((unsigned)(unsigned short)s)<<16; return x.f;
}
__device__ __forceinline__ short f2bs(float x){
  __hip_bfloat16 b = __float2bfloat16(x);
  return *reinterpret_cast<short*>(&b);
}
__device__ __forceinline__ float wsum64(float v){
  #pragma unroll
  for(int m=1;m<64;m<<=1) v += __shfl_xor(v,m,64);
  return v;
}
__device__ __forceinline__ float wsum16(float v){
  #pragma unroll
  for(int m=1;m<16;m<<=1) v += __shfl_xor(v,m,64);
  return v;
}
__device__ __forceinline__ float2 ldbf2(const __hip_bfloat16* p){
  __hip_bfloat162 b = *(const __hip_bfloat162*)p;
  return make_float2(__bfloat162float(b.x), __bfloat162float(b.y));
}
__device__ __forceinline__ int lb_(const int* __restrict__ a, int n, int key){
  int lo=0, hi=n;
  while(lo<hi){ int mid=(lo+hi)>>1; if(a[mid]<key) lo=mid+1; else hi=mid; }
  return lo;
}

// ---------------- CSR counts ----------------
__global__ void count_dst(const int* __restrict__ ei, int* __restrict__ counts, int E){
  int e = blockIdx.x*256+threadIdx.x;
  if(e<E) atomicAdd(&counts[ei[E+e]],1);
}
__global__ void scan1(const int* __restrict__ counts, int* __restrict__ tmp,
                      int* __restrict__ bsums, int N){
  __shared__ int lds[256];
  int t = threadIdx.x; int idx = blockIdx.x*256+t;
  int v = (idx<N)? counts[idx]:0;
  lds[t]=v; __syncthreads();
  for(int off=1;off<256;off<<=1){
    int x = (t>=off)? lds[t-off]:0;
    __syncthreads();
    lds[t]+=x; __syncthreads();
  }
  if(idx<N) tmp[idx]=lds[t];
  if(t==255) bsums[blockIdx.x]=lds[255];
}
__global__ void scan2(const int* __restrict__ bsums, int* __restrict__ boffs, int nb){
  __shared__ int lds[256];
  int t=threadIdx.x;
  int v = (t<nb)? bsums[t]:0;
  lds[t]=v; __syncthreads();
  for(int off=1;off<256;off<<=1){
    int x=(t>=off)?lds[t-off]:0;
    __syncthreads();
    lds[t]+=x; __syncthreads();
  }
  if(t<nb) boffs[t] = lds[t]-v; // exclusive
}
__global__ void finalize_rs(const int* __restrict__ tmp, const int* __restrict__ boffs,
                            int* __restrict__ row_start, int N){
  int idx = blockIdx.x*256+threadIdx.x;
  if(idx<N) row_start[idx+1] = tmp[idx] + boffs[idx>>8];
  if(idx==0) row_start[0]=0;
}

// ---------------- edge features (sorted by dst) ----------------
__global__ void edge_prep(const float* __restrict__ pos, const float* __restrict__ ew,
                          const int* __restrict__ ei, const int* __restrict__ rowst,
                          int* __restrict__ counts2, float* __restrict__ efs,
                          int* __restrict__ esrc, int E){
  int e = blockIdx.x*256 + threadIdx.x;
  if(e>=E) return;
  int s = ei[e], d = ei[E+e];
  float dx = pos[d*3+0]-pos[s*3+0];
  float dy = pos[d*3+1]-pos[s*3+1];
  float dz = pos[d*3+2]-pos[s*3+2];
  float D = sqrtf(dx*dx+dy*dy+dz*dz);
  float x = D*0.1f;
  float cut = 0.f;
  if(x < 1.f){ float x3=x*x*x, x4=x3*x, x5=x4*x; cut = 1.f - 6.f*x5 + 15.f*x4 - 10.f*x3; }
  float ed = expf(-D);
  const double e10 = 4.5399929762484854e-05; // exp(-10)
  const float step  = (float)((e10 - 1.0)/8.0);
  const float width = (float)((4.5/(1.0-e10))*(4.5/(1.0-e10)));
  float r12[12];
  #pragma unroll
  for(int k=0;k<KRBF;k++){
    float c = 1.0f + k*step;
    float dd = ed - c;
    r12[k] = cut*expf(-width*dd*dd);
  }
  r12[9] = ew[e]; r12[10]=0.f; r12[11]=0.f;
  int p = rowst[d] + atomicAdd(&counts2[d],1);
  float* o = efs + (size_t)p*12;
  *(float4*)&o[0] = *(float4*)&r12[0];
  *(float4*)&o[4] = *(float4*)&r12[4];
  *(float4*)&o[8] = *(float4*)&r12[8];
  esrc[p] = s;
}

// ---------------- weight packing: fp32 -> bf16, [col'][k], fragment-permuted ----------------
// within each 128-col block, packed position p holds global col g = (p&15)*8 + (p>>4)
__global__ void pack_w(const float* __restrict__ Wq, const float* __restrict__ Wk,
                       const float* __restrict__ Wv, const float* __restrict__ Wsk,
                       const float* __restrict__ bq, const float* __restrict__ bk,
                       const float* __restrict__ bv, const float* __restrict__ bsk,
                       const float* __restrict__ We,
                       const float* __restrict__ W1, const float* __restrict__ W2,
                       const float* __restrict__ W3,
                       __hip_bfloat16* __restrict__ Wqkvs, float* __restrict__ bqkvs,
                       __hip_bfloat16* __restrict__ Wffn){
  int idx = blockIdx.x*256 + threadIdx.x;
  const int QT = NLAYER*QWCOLS*128;
  const int FT = NLAYER*3*128*128;
  const int BT = NLAYER*QWCOLS;
  if(idx < QT){
    int l = idx / (QWCOLS*128);
    int rem = idx - l*(QWCOLS*128);
    int colp = rem >> 7, k = rem & 127;
    int b = colp >> 7, p = colp & 127;
    int g = ((p&15)<<3) + (p>>4);
    int gcol = b*128 + g;
    float v = 0.f;
    if(gcol < 512){
      const float* src = (gcol<128)?Wq:((gcol<256)?Wk:((gcol<384)?Wv:Wsk));
      v = src[(size_t)l*16384 + k*128 + (gcol&127)];
    } else if(gcol < 552){
      int j = gcol-512; int h=j/10; int r=j-10*h;
      const float* wq = Wq + (size_t)l*16384 + k*128;
      const float* we = We + (size_t)l*1280 + r*128;
      float acc=0.f;
      #pragma unroll 8
      for(int c=32*h;c<32*h+32;c++) acc = fmaf(wq[c], we[c], acc);
      v = acc;
    }
    Wqkvs[idx] = __float2bfloat16(v);
  } else if(idx < QT+FT){
    int j = idx - QT;
    int k = j & 127; int colp = (j>>7)&127; int f = (j>>14)%3; int l = j/(3*16384);
    int g = ((colp&15)<<3) + (colp>>4);
    const float* src = (f==0)?W1:((f==1)?W2:W3);
    Wffn[j] = __float2bfloat16(src[(size_t)l*16384 + k*128 + g]);
  } else if(idx < QT+FT+BT){
    int j = idx - QT - FT;
    int l = j/QWCOLS; int col = j - l*QWCOLS;   // bias stays in NATURAL col order
    float v = 0.f;
    if(col<512){
      const float* src = (col<128)?bq:((col<256)?bk:((col<384)?bv:bsk));
      v = src[l*128 + (col&127)];
    } else if(col<552){
      int jj=col-512; int h=jj/10; int r=jj-10*h;
      const float* bqp = bq + l*128;
      const float* we = We + (size_t)l*1280 + r*128;
      float acc=0.f;
      for(int c=32*h;c<32*h+32;c++) acc = fmaf(bqp[c], we[c], acc);
      v = acc;
    }
    bqkvs[j] = v;
  }
}

// ---------------- LayerNorm (wave per node) fp32 -> bf16 (layer 0 only) ----------------
__global__ void ln_node(const float* __restrict__ h, const float* __restrict__ g,
                        const float* __restrict__ b, __hip_bfloat16* __restrict__ hn, int N){
  int n = blockIdx.x*4 + (threadIdx.x>>6);
  if(n>=N) return;
  int lane = threadIdx.x & 63;
  int c = 2*lane;
  float2 v = *(const float2*)&h[(size_t)n*HID + c];
  float s1 = wsum64(v.x+v.y);
  float s2 = wsum64(v.x*v.x+v.y*v.y);
  float mu = s1*(1.f/HID);
  float var = s2*(1.f/HID) - mu*mu;
  float rs = rsqrtf(var + 1e-5f);
  __hip_bfloat162 o;
  o.x = __float2bfloat16((v.x-mu)*rs*g[c]   + b[c]);
  o.y = __float2bfloat16((v.y-mu)*rs*g[c+1] + b[c+1]);
  *(__hip_bfloat162*)&hn[(size_t)n*HID + c] = o;
}

// ---------------- MFMA bf16 GEMM, fragment-native ----------------
// MI: rows per block = MI*64 (each of 4 waves owns MI*16 rows).
// W tile (128 cols) staged in LDS (pad 140 -> <=2-way banks); A fragments direct from global.
// Lane (ql,il) owns cols il*8..il*8+7 of its rows -> bf16x8 coalesced epilogue stores.
// MODE 0: qkvs col-block routing to qs/kvb.  MODE 1: softplus -> bf16.
// MODE 2: softplus + res + row-LN -> fp32 h + bf16 hn.
template<int MODE, int MI>
__global__ __launch_bounds__(256) void gemm_t(
    const __hip_bfloat16* __restrict__ A, const __hip_bfloat16* __restrict__ Wt,
    const float* __restrict__ bias, const __hip_bfloat16* __restrict__ res,
    void* __restrict__ out0, void* __restrict__ out1,
    const float* __restrict__ lng, const float* __restrict__ lnb, int N){
  __shared__ __hip_bfloat16 Ws[128][140];
  int row0 = blockIdx.y*(MI*64);
  int cb = blockIdx.x;
  int tid = threadIdx.x;
  {
    int chunk = tid&15, rbase = tid>>4;
    #pragma unroll
    for(int i=0;i<8;i++){
      int p = rbase + 16*i;
      *(float4*)&Ws[p][chunk*8] =
        *(const float4*)&Wt[(size_t)(cb*128+p)*128 + chunk*8];
    }
  }
  int lane = tid&63;
  int m0 = (tid>>6)*(MI*16);
  int ql = lane>>4, il = lane&15;
  // A fragments (direct global, row-clamped)
  bf16x8 af[MI][4];
  #pragma unroll
  for(int mi=0;mi<MI;mi++){
    int r = row0 + m0 + mi*16 + il;
    r = (r < N) ? r : (N-1);
    const __hip_bfloat16* ap = A + (size_t)r*128 + ql*8;
    #pragma unroll
    for(int kc=0;kc<4;kc++) af[mi][kc] = *(const bf16x8*)(ap + kc*32);
  }
  __syncthreads();
  f32x4 acc[MI][8];
  #pragma unroll
  for(int mi=0;mi<MI;mi++)
    #pragma unroll
    for(int nj=0;nj<8;nj++) acc[mi][nj] = (f32x4){0.f,0.f,0.f,0.f};
  #pragma unroll
  for(int kc=0;kc<4;kc++){
    #pragma unroll
    for(int nj=0;nj<8;nj++){
      bf16x8 bb = *(bf16x8*)&Ws[nj*16+il][kc*32+ql*8];
      #pragma unroll
      for(int mi=0;mi<MI;mi++)
        acc[mi][nj] = __builtin_amdgcn_mfma_f32_16x16x32_bf16(af[mi][kc], bb, acc[mi][nj], 0,0,0);
    }
  }
  // bias for this lane's 8 contiguous cols
  float bl8[8];
  {
    float4 b0 = *(const float4*)&bias[cb*128 + il*8];
    float4 b1 = *(const float4*)&bias[cb*128 + il*8 + 4];
    bl8[0]=b0.x; bl8[1]=b0.y; bl8[2]=b0.z; bl8[3]=b0.w;
    bl8[4]=b1.x; bl8[5]=b1.y; bl8[6]=b1.z; bl8[7]=b1.w;
  }
  if(MODE==0){
    __hip_bfloat16* qsO = (__hip_bfloat16*)out0;
    __hip_bfloat16* kvO = (__hip_bfloat16*)out1;
    #pragma unroll
    for(int mi=0;mi<MI;mi++){
      #pragma unroll
      for(int r=0;r<4;r++){
        int rr = row0 + m0 + mi*16 + ql*4 + r;
        if(rr >= N) continue;
        bf16x8 o;
        #pragma unroll
        for(int nj=0;nj<8;nj++) o[nj] = f2bs(acc[mi][nj][r] + bl8[nj]);
        __hip_bfloat16* dst; bool ok = true;
        if(cb==0)      dst = qsO + (size_t)rr*QSSTR + il*8;
        else if(cb==1) dst = kvO + (size_t)rr*KVSTR + il*8;
        else if(cb==2) dst = kvO + (size_t)rr*KVSTR + 128 + il*8;
        else if(cb==3) dst = qsO + (size_t)rr*QSSTR + 128 + il*8;
        else { dst = qsO + (size_t)rr*QSSTR + 256 + il*8; ok = (il < 5); }
        if(ok) *(bf16x8*)dst = o;
      }
    }
  } else if(MODE==1){
    __hip_bfloat16* o0 = (__hip_bfloat16*)out0;
    #pragma unroll
    for(int mi=0;mi<MI;mi++){
      #pragma unroll
      for(int r=0;r<4;r++){
        int rr = row0 + m0 + mi*16 + ql*4 + r;
        if(rr >= N) continue;
        bf16x8 o;
        #pragma unroll
        for(int nj=0;nj<8;nj++) o[nj] = f2bs(sp_(acc[mi][nj][r] + bl8[nj]));
        *(bf16x8*)&o0[(size_t)rr*128 + il*8] = o;
      }
    }
  } else {
    float* hout = (float*)out0;
    __hip_bfloat16* hnout = (__hip_bfloat16*)out1;
    float4 lg0 = *(const float4*)&lng[il*8];
    float4 lg1 = *(const float4*)&lng[il*8+4];
    float4 lb0 = *(const float4*)&lnb[il*8];
    float4 lb1 = *(const float4*)&lnb[il*8+4];
    float lg8[8] = {lg0.x,lg0.y,lg0.z,lg0.w,lg1.x,lg1.y,lg1.z,lg1.w};
    float lb8[8] = {lb0.x,lb0.y,lb0.z,lb0.w,lb1.x,lb1.y,lb1.z,lb1.w};
    #pragma unroll
    for(int mi=0;mi<MI;mi++){
      #pragma unroll
      for(int r=0;r<4;r++){
        int rr = row0 + m0 + mi*16 + ql*4 + r;
        if(rr >= N) continue;   // uniform across il (shfl group safe)
        bf16x8 rv = *(const bf16x8*)&res[(size_t)rr*128 + il*8];
        float t8[8]; float s1=0.f, s2=0.f;
        #pragma unroll
        for(int nj=0;nj<8;nj++){
          float x = sp_(acc[mi][nj][r] + bl8[nj]) + b2f(rv[nj]);
          t8[nj] = x; s1 += x; s2 += x*x;
        }
        s1 = wsum16(s1); s2 = wsum16(s2);
        float mu = s1*(1.f/128.f);
        float var = s2*(1.f/128.f) - mu*mu;
        float rs = rsqrtf(var + 1e-5f);
        float4 h0 = make_float4(t8[0],t8[1],t8[2],t8[3]);
        float4 h1 = make_float4(t8[4],t8[5],t8[6],t8[7]);
        *(float4*)&hout[(size_t)rr*128 + il*8]     = h0;
        *(float4*)&hout[(size_t)rr*128 + il*8 + 4] = h1;
        bf16x8 o;
        #pragma unroll
        for(int nj=0;nj<8;nj++) o[nj] = f2bs((t8[nj]-mu)*rs*lg8[nj] + lb8[nj]);
        *(bf16x8*)&hnout[(size_t)rr*128 + il*8] = o;
      }
    }
  }
}

// ---------------- fused attention: 8 edges/wave, 8 lanes/edge, 16 ch/lane ----------------
__global__ __launch_bounds__(256) void attn_fused3(
    const __hip_bfloat16* __restrict__ qs, const __hip_bfloat16* __restrict__ kvb,
    const float* __restrict__ efs, const int* __restrict__ esrc,
    const float* __restrict__ WeL, const int* __restrict__ rowst,
    float* __restrict__ att, int N){
  int n = blockIdx.x*4 + (threadIdx.x>>6);
  if(n>=N) return;
  int lane = threadIdx.x & 63;
  int eg = lane>>3, sl = lane&7;
  int c16 = sl*16, hd = sl>>1;
  const __hip_bfloat16* rowq = qs + (size_t)n*QSSTR;
  float q16[16];
  {
    bf16x8 qa = *(const bf16x8*)&rowq[c16];
    bf16x8 qb = *(const bf16x8*)&rowq[c16+8];
    #pragma unroll
    for(int j=0;j<8;j++){ q16[j] = b2f(qa[j]); q16[8+j] = b2f(qb[j]); }
  }
  float QW[10];
  #pragma unroll
  for(int r=0;r<10;r++) QW[r] = __bfloat162float(rowq[256 + hd*10 + r]);
  int lo = rowst[n], hi = rowst[n+1];
  float ssum = 0.f, a16[16], S[10];
  #pragma unroll
  for(int j=0;j<16;j++) a16[j]=0.f;
  #pragma unroll
  for(int r=0;r<10;r++) S[r]=0.f;
  for(int i=lo+eg; i<hi; i+=8){
    int s = esrc[i];
    const __hip_bfloat16* kr = kvb + (size_t)s*KVSTR;
    bf16x8 ka = *(const bf16x8*)&kr[c16];
    bf16x8 kb = *(const bf16x8*)&kr[c16+8];
    bf16x8 va = *(const bf16x8*)&kr[128+c16];
    bf16x8 vb = *(const bf16x8*)&kr[128+c16+8];
    const float* ef = efs + (size_t)i*12;
    float4 e0 = *(const float4*)&ef[0];
    float4 e1 = *(const float4*)&ef[4];
    float2 e2 = *(const float2*)&ef[8];
    float d = 0.f;
    #pragma unroll
    for(int j=0;j<8;j++){
      d = fmaf(q16[j],   b2f(ka[j]), d);
      d = fmaf(q16[8+j], b2f(kb[j]), d);
    }
    d += __shfl_xor(d,1,64);     // partner lane of same head (32 ch total)
    float lg = d;
    lg = fmaf(e0.x,QW[0],lg); lg = fmaf(e0.y,QW[1],lg);
    lg = fmaf(e0.z,QW[2],lg); lg = fmaf(e0.w,QW[3],lg);
    lg = fmaf(e1.x,QW[4],lg); lg = fmaf(e1.y,QW[5],lg);
    lg = fmaf(e1.z,QW[6],lg); lg = fmaf(e1.w,QW[7],lg);
    lg = fmaf(e2.x,QW[8],lg); lg = fmaf(e2.y,QW[9],lg);
    lg *= 0.17677669529663687f;
    lg = fminf(lg, 80.f);
    float w = __expf(lg);
    ssum += w;
    #pragma unroll
    for(int j=0;j<8;j++){
      a16[j]   = fmaf(w, b2f(va[j]), a16[j]);
      a16[8+j] = fmaf(w, b2f(vb[j]), a16[8+j]);
    }
    S[0]=fmaf(w,e0.x,S[0]); S[1]=fmaf(w,e0.y,S[1]); S[2]=fmaf(w,e0.z,S[2]);
    S[3]=fmaf(w,e0.w,S[3]); S[4]=fmaf(w,e1.x,S[4]); S[5]=fmaf(w,e1.y,S[5]);
    S[6]=fmaf(w,e1.z,S[6]); S[7]=fmaf(w,e1.w,S[7]); S[8]=fmaf(w,e2.x,S[8]);
    S[9]=fmaf(w,e2.y,S[9]);
  }
  #pragma unroll
  for(int m=8;m<64;m<<=1){
    ssum += __shfl_xor(ssum,m,64);
    #pragma unroll
    for(int j=0;j<16;j++) a16[j] += __shfl_xor(a16[j],m,64);
    #pragma unroll
    for(int r=0;r<10;r++) S[r] += __shfl_xor(S[r],m,64);
  }
  if(eg==0){
    float inv = (hi>lo)? 1.f/ssum : 0.f;
    float o16[16];
    #pragma unroll
    for(int j=0;j<16;j++) o16[j]=a16[j];
    #pragma unroll
    for(int r=0;r<10;r++){
      float s=S[r];
      const float* wp = &WeL[r*128 + c16];
      float4 w0 = *(const float4*)&wp[0];
      float4 w1 = *(const float4*)&wp[4];
      float4 w2 = *(const float4*)&wp[8];
      float4 w3 = *(const float4*)&wp[12];
      o16[0]=fmaf(s,w0.x,o16[0]);  o16[1]=fmaf(s,w0.y,o16[1]);
      o16[2]=fmaf(s,w0.z,o16[2]);  o16[3]=fmaf(s,w0.w,o16[3]);
      o16[4]=fmaf(s,w1.x,o16[4]);  o16[5]=fmaf(s,w1.y,o16[5]);
      o16[6]=fmaf(s,w1.z,o16[6]);  o16[7]=fmaf(s,w1.w,o16[7]);
      o16[8]=fmaf(s,w2.x,o16[8]);  o16[9]=fmaf(s,w2.y,o16[9]);
      o16[10]=fmaf(s,w2.z,o16[10]); o16[11]=fmaf(s,w2.w,o16[11]);
      o16[12]=fmaf(s,w3.x,o16[12]); o16[13]=fmaf(s,w3.y,o16[13]);
      o16[14]=fmaf(s,w3.z,o16[14]); o16[15]=fmaf(s,w3.w,o16[15]);
    }
    float* ap = att + (size_t)n*128 + c16;
    #pragma unroll
    for(int q4=0;q4<4;q4++){
      float4 v = make_float4(o16[q4*4]*inv, o16[q4*4+1]*inv,
                             o16[q4*4+2]*inv, o16[q4*4+3]*inv);
      *(float4*)&ap[q4*4] = v;
    }
  }
}

// ---------------- beta-gate + residual + softplus + LN (wave per node) ----------------
__global__ void combine_ln(const float* __restrict__ att, const __hip_bfloat16* __restrict__ qs,
                           const __hip_bfloat16* __restrict__ hn, const float* __restrict__ Wb,
                           const float* __restrict__ g, const float* __restrict__ b,
                           __hip_bfloat16* __restrict__ hn2, int N){
  int n = blockIdx.x*4 + (threadIdx.x>>6);
  if(n>=N) return;
  int lane = threadIdx.x&63;
  int c = 2*lane;
  float2 o  = *(const float2*)&att[(size_t)n*HID+c];
  float2 xr = ldbf2(&qs[(size_t)n*QSSTR + 128 + c]);
  float bl = o.x*Wb[c] + o.y*Wb[c+1]
           + xr.x*Wb[HID+c] + xr.y*Wb[HID+c+1]
           + (o.x-xr.x)*Wb[2*HID+c] + (o.y-xr.y)*Wb[2*HID+c+1];
  bl = wsum64(bl);
  float beta = sigm_(bl);
  float u0 = beta*xr.x + (1.f-beta)*o.x;
  float u1 = beta*xr.y + (1.f-beta)*o.y;
  float2 hnv = ldbf2(&hn[(size_t)n*HID+c]);
  float h0 = hnv.x + sp_(u0);
  float h1 = hnv.y + sp_(u1);
  float s1 = wsum64(h0+h1);
  float s2 = wsum64(h0*h0+h1*h1);
  float mu = s1*(1.f/HID);
  float var = s2*(1.f/HID)-mu*mu;
  float rs = rsqrtf(var+1e-5f);
  __hip_bfloat162 outv;
  outv.x = __float2bfloat16((h0-mu)*rs*g[c]+b[c]);
  outv.y = __float2bfloat16((h1-mu)*rs*g[c+1]+b[c+1]);
  *(__hip_bfloat162*)&hn2[(size_t)n*HID+c] = outv;
}

// ---------------- pooling + output head (block per graph) ----------------
__global__ void pool_head(const float* __restrict__ h, const int* __restrict__ batch,
                          const float* __restrict__ Wo1, const float* __restrict__ bo1,
                          const float* __restrict__ Wo2, const float* __restrict__ bo2,
                          float* __restrict__ out, int N){
  int gid = blockIdx.x;
  int t = threadIdx.x;  // 128 threads
  int lo = lb_(batch, N, gid), hi = lb_(batch, N, gid+1);
  __shared__ float pl[128];
  __shared__ float red[128];
  float s = 0.f;
  for(int i=lo;i<hi;i++) s += h[(size_t)i*HID + t];
  pl[t] = s;
  __syncthreads();
  float acc = bo1[t];
  for(int c=0;c<128;c++) acc = fmaf(pl[c], Wo1[c*HID+t], acc);
  red[t] = sp_(acc)*Wo2[t];
  __syncthreads();
  for(int off=64;off>0;off>>=1){
    if(t<off) red[t]+=red[t+off];
    __syncthreads();
  }
  if(t==0) out[gid] = red[0] + bo2[0];
}

extern "C" void kernel_launch(void* const* d_in, const int* in_sizes, int n_in,
                              void* d_out, int out_size, void* d_ws, size_t ws_size,
                              hipStream_t stream){
  const float* h_in = (const float*)d_in[0];
  const float* pos  = (const float*)d_in[1];
  const float* ew   = (const float*)d_in[2];
  const float* Wq = (const float*)d_in[3];  const float* bq = (const float*)d_in[4];
  const float* Wk = (const float*)d_in[5];  const float* bk = (const float*)d_in[6];
  const float* Wv = (const float*)d_in[7];  const float* bv = (const float*)d_in[8];
  const float* We = (const float*)d_in[9];
  const float* Wsk= (const float*)d_in[10]; const float* bsk=(const float*)d_in[11];
  const float* Wbeta=(const float*)d_in[12];
  const float* W1=(const float*)d_in[13]; const float* b1=(const float*)d_in[14];
  const float* W2=(const float*)d_in[15]; const float* b2=(const float*)d_in[16];
  const float* W3=(const float*)d_in[17]; const float* b3=(const float*)d_in[18];
  const float* lng=(const float*)d_in[19]; const float* lnb=(const float*)d_in[20];
  const float* Wo1=(const float*)d_in[21]; const float* bo1=(const float*)d_in[22];
  const float* Wo2=(const float*)d_in[23]; const float* bo2=(const float*)d_in[24];
  const int* ei    = (const int*)d_in[25];
  const int* batch = (const int*)d_in[26];
  int N = in_sizes[0]/HID;
  int E = in_sizes[2];
  int G = out_size;
  float* out = (float*)d_out;

  char* ws = (char*)d_ws;
  size_t off=0;
  auto alloc=[&](size_t bytes)->char*{
    char* p = ws + off;
    off = (off + bytes + 255) & ~(size_t)255;
    return p;
  };
  float* efs   =(float*)alloc((size_t)E*12*4);
  int* esrc    =(int*)  alloc((size_t)E*4);
  int* counts  =(int*)  alloc((size_t)N*4);
  int* counts2 =(int*)  alloc((size_t)N*4);
  int* rowst   =(int*)  alloc((size_t)(N+1)*4);
  int* tmp     =(int*)  alloc((size_t)N*4);
  int* bsums   =(int*)  alloc(256*4);
  int* boffs   =(int*)  alloc(256*4);
  __hip_bfloat16* hn   =(__hip_bfloat16*)alloc((size_t)N*HID*2);
  __hip_bfloat16* hn2  =(__hip_bfloat16*)alloc((size_t)N*HID*2);
  __hip_bfloat16* qsb  =(__hip_bfloat16*)alloc((size_t)N*QSSTR*2);
  __hip_bfloat16* kvb  =(__hip_bfloat16*)alloc((size_t)N*KVSTR*2);
  __hip_bfloat16* f1   =(__hip_bfloat16*)alloc((size_t)N*HID*2);
  __hip_bfloat16* f2   =(__hip_bfloat16*)alloc((size_t)N*HID*2);
  float* att   =(float*)alloc((size_t)N*HID*4);
  float* hcur  =(float*)alloc((size_t)N*HID*4);
  __hip_bfloat16* Wqkvs_t =(__hip_bfloat16*)alloc((size_t)NLAYER*QWCOLS*128*2);
  __hip_bfloat16* Wffn_t  =(__hip_bfloat16*)alloc((size_t)NLAYER*3*128*128*2);
  float* bqkvs =(float*)alloc((size_t)NLAYER*QWCOLS*4);

  int ebl = (E+255)/256;
  int nb  = (N+255)/256;
  int nwb = (N+3)/4;
  int nrb128 = (N+127)/128;
  int nrb64  = (N+63)/64;
  dim3 gqkvs(QWCOLS/128, nrb128);   // 5 x 391
  dim3 gffn(1, nrb64);              // 1 x 782

  hipMemsetAsync(counts, 0, (size_t)N*4, stream);
  hipMemsetAsync(counts2,0, (size_t)N*4, stream);
  count_dst<<<ebl,256,0,stream>>>(ei,counts,E);
  scan1<<<nb,256,0,stream>>>(counts,tmp,bsums,N);
  scan2<<<1,256,0,stream>>>(bsums,boffs,nb);
  finalize_rs<<<nb,256,0,stream>>>(tmp,boffs,rowst,N);
  edge_prep<<<ebl,256,0,stream>>>(pos,ew,ei,rowst,counts2,efs,esrc,E);
  {
    int tot = NLAYER*QWCOLS*128 + NLAYER*3*128*128 + NLAYER*QWCOLS;
    pack_w<<<(tot+255)/256,256,0,stream>>>(Wq,Wk,Wv,Wsk,bq,bk,bv,bsk,We,W1,W2,W3,
                                           Wqkvs_t,bqkvs,Wffn_t);
  }

  ln_node<<<nwb,256,0,stream>>>(h_in,lng,lnb,hn,N);
  for(int l=0;l<NLAYER;l++){
    const float* We_l = We + (size_t)l*(KRBF+1)*HID;
    const float* Wb_l = Wbeta + (size_t)l*3*HID;
    const float* b1_l = b1 + (size_t)l*HID;
    const float* b2_l = b2 + (size_t)l*HID;
    const float* b3_l = b3 + (size_t)l*HID;

    gemm_t<0,2><<<gqkvs,256,0,stream>>>(hn, Wqkvs_t + (size_t)l*QWCOLS*128,
                                        bqkvs + l*QWCOLS, nullptr, qsb, kvb,
                                        lng, lnb, N);
    attn_fused3<<<nwb,256,0,stream>>>(qsb,kvb,efs,esrc,We_l,rowst,att,N);
    combine_ln<<<nwb,256,0,stream>>>(att,qsb,hn,Wb_l,lng,lnb,hn2,N);
    gemm_t<1,1><<<gffn,256,0,stream>>>(hn2, Wffn_t + (size_t)(l*3+0)*16384, b1_l,
                                       nullptr, f1, nullptr, lng, lnb, N);
    gemm_t<1,1><<<gffn,256,0,stream>>>(f1,  Wffn_t + (size_t)(l*3+1)*16384, b2_l,
                                       nullptr, f2, nullptr, lng, lnb, N);
    gemm_t<2,1><<<gffn,256,0,stream>>>(f2,  Wffn_t + (size_t)(l*3+2)*16384, b3_l,
                                       hn2, hcur, hn, lng, lnb, N);
  }
  pool_head<<<G,128,0,stream>>>(hcur,batch,Wo1,bo1,Wo2,bo2,out,N);
}